// Round 6
// baseline (457.351 us; speedup 1.0000x reference)
//
#include <hip/hip_runtime.h>
#include <hip/hip_bf16.h>
#include <cstddef>

// ---- problem constants ----
#define Bc   2
#define Lc   8192
#define TGT  6146          // L - RF, RF = 2046
#define NL   20            // layers
#define RCc  32
#define DCc  32
#define SCc  1024
#define ECc  512
#define OCc  256
#define KTOT (NL * DCc)    // 640
#define TTILES 49          // ceil(TGT/128)

typedef __attribute__((ext_vector_type(4))) float f32x4;
typedef __attribute__((ext_vector_type(8))) short bf16x8;
typedef __attribute__((ext_vector_type(4))) int i32x4;
typedef __attribute__((ext_vector_type(2))) int i32x2;

typedef __attribute__((address_space(1))) void* as1v;
typedef __attribute__((address_space(3))) void* as3v;

// ============================================================
// K0: input 1x1 conv  (B,256,L) x (32,256) -> res (B,32,L)
// ============================================================
__global__ __launch_bounds__(256) void input_conv(
    const float* __restrict__ x,   // [B][256][L]
    const float* __restrict__ w,   // [32][256]
    float* __restrict__ res_out)   // [B][32][L]
{
    __shared__ float ws[32][256];
    __shared__ float xs[64][64];
    int tid = threadIdx.x;
    int b   = blockIdx.y;
    int t0  = blockIdx.x * 64;

    for (int idx = tid; idx < 32 * 256; idx += 256)
        ws[idx >> 8][idx & 255] = w[idx];

    int tl = tid & 63, qq = tid >> 6, oc0 = qq * 8;
    float acc[8] = {};

    for (int icc = 0; icc < 4; ++icc) {
        __syncthreads();
        for (int idx = tid; idx < 64 * 64; idx += 256) {
            int icl = idx >> 6, tll = idx & 63;
            xs[icl][tll] = x[((size_t)b * 256 + icc * 64 + icl) * Lc + t0 + tll];
        }
        __syncthreads();
        for (int icl = 0; icl < 64; icl += 4) {
            float x0 = xs[icl][tl], x1 = xs[icl + 1][tl];
            float x2 = xs[icl + 2][tl], x3 = xs[icl + 3][tl];
#pragma unroll
            for (int j = 0; j < 8; ++j) {
                const float4 w4 = *(const float4*)&ws[oc0 + j][icc * 64 + icl];
                acc[j] += w4.x * x0 + w4.y * x1 + w4.z * x2 + w4.w * x3;
            }
        }
    }
#pragma unroll
    for (int j = 0; j < 8; ++j)
        res_out[((size_t)b * 32 + oc0 + j) * Lc + t0 + tl] = acc[j];
}

// ============================================================
// weight pack for layers: wp[li][sect][ic][oc], sect = f0,f1,g0,g1,r
// (values exact fp32; layout only)
// ============================================================
__global__ void pack_layerw(const float* __restrict__ filt,  // [NL][32][32][2]
                            const float* __restrict__ gate,
                            const float* __restrict__ resw,  // [NL][32][32]
                            float* __restrict__ wp)
{
    int idx = blockIdx.x * 256 + threadIdx.x;
    if (idx >= NL * 5120) return;
    int li = idx / 5120, r = idx % 5120;
    int sect = r >> 10, ic = (r >> 5) & 31, oc = r & 31;
    float v;
    if (sect == 0)      v = filt[(size_t)li * 2048 + (oc * 32 + ic) * 2 + 0];
    else if (sect == 1) v = filt[(size_t)li * 2048 + (oc * 32 + ic) * 2 + 1];
    else if (sect == 2) v = gate[(size_t)li * 2048 + (oc * 32 + ic) * 2 + 0];
    else if (sect == 3) v = gate[(size_t)li * 2048 + (oc * 32 + ic) * 2 + 1];
    else                v = resw[(size_t)li * 1024 + oc * 32 + ic];
    wp[idx] = v;
}

// ============================================================
// per-layer v4: 512 thr, 64-t tile, 4 oc/thread (wave-uniform).
// Weights read DIRECT from global with wave-uniform addresses ->
// s_load via constant cache (scalar pipe). Zero LDS in conv loop.
// x column in registers (static indexing only). One barrier.
// ============================================================
template <bool SKIPRES>
__global__ __launch_bounds__(512) void layer_v4(
    const float* __restrict__ res_in,   // [B][32][L]
    float* __restrict__ res_out,        // [B][32][L]
    __hip_bfloat16* __restrict__ outsT, // [B*TGT][640]
    const float* __restrict__ wl,       // [5][32][32] this layer
    const float* __restrict__ cond,     // [B][5]
    const float* __restrict__ gcf,      // [5]
    const float* __restrict__ gcs,      // [5]
    int dil, int li)
{
    __shared__ float osh[32][64];

    int tid = threadIdx.x;
    int b   = blockIdx.y;
    int t0  = blockIdx.x * 64;
    int tl  = tid & 63;
    int oc0 = __builtin_amdgcn_readfirstlane((tid >> 6) * 4);
    int t   = t0 + tl;

    // x column into registers (coalesced per-ic loads; static indices)
    const float* rbase = res_in + (size_t)b * 32 * Lc + t;
    float x0[32], xm[32];
#pragma unroll
    for (int ic = 0; ic < 32; ++ic) {
        x0[ic] = rbase[ic * Lc];
        xm[ic] = (t >= dil) ? rbase[ic * Lc - dil] : 0.f;
    }

    float gf = gcf[0] * cond[b * 5 + 0] + gcf[1] * cond[b * 5 + 1] +
               gcf[2] * cond[b * 5 + 2] + gcf[3] * cond[b * 5 + 3] +
               gcf[4] * cond[b * 5 + 4];
    float gg = gcs[0] * cond[b * 5 + 0] + gcs[1] * cond[b * 5 + 1] +
               gcs[2] * cond[b * 5 + 2] + gcs[3] * cond[b * 5 + 3] +
               gcs[4] * cond[b * 5 + 4];

    float facc[4], gacc[4];
#pragma unroll
    for (int j = 0; j < 4; ++j) { facc[j] = gf; gacc[j] = gg; }

#pragma unroll
    for (int ic = 0; ic < 32; ++ic) {
        // wave-uniform addresses -> scalar loads (constant cache)
        const float4 f0 = *(const float4*)(wl +        ic * 32 + oc0);
        const float4 f1 = *(const float4*)(wl + 1024 + ic * 32 + oc0);
        const float4 g0 = *(const float4*)(wl + 2048 + ic * 32 + oc0);
        const float4 g1 = *(const float4*)(wl + 3072 + ic * 32 + oc0);
        float a = xm[ic], c = x0[ic];
        facc[0] += f0.x * a + f1.x * c;  gacc[0] += g0.x * a + g1.x * c;
        facc[1] += f0.y * a + f1.y * c;  gacc[1] += g0.y * a + g1.y * c;
        facc[2] += f0.z * a + f1.z * c;  gacc[2] += g0.z * a + g1.z * c;
        facc[3] += f0.w * a + f1.w * c;  gacc[3] += g0.w * a + g1.w * c;
    }

    float o[4];
#pragma unroll
    for (int j = 0; j < 4; ++j) {
        float th = 1.f - 2.f / (__expf(2.f * facc[j]) + 1.f);  // tanh
        float sg = 1.f / (1.f + __expf(-gacc[j]));             // sigmoid
        o[j] = th * sg;
        if (!SKIPRES) osh[oc0 + j][tl] = o[j];
    }

    // skip-output store (bf16, time-major), 8B per thread
    if (t >= Lc - TGT) {
        int ts = t - (Lc - TGT);
        union { i32x2 v; __hip_bfloat16 h[4]; } u;
#pragma unroll
        for (int j = 0; j < 4; ++j) u.h[j] = __float2bfloat16(o[j]);
        *(i32x2*)(outsT + ((size_t)(b * TGT + ts)) * KTOT + li * 32 + oc0) = u.v;
    }

    if (!SKIPRES) {
        __syncthreads();   // osh complete
        float racc[4];
#pragma unroll
        for (int j = 0; j < 4; ++j) racc[j] = rbase[(oc0 + j) * Lc];  // global reload (no dyn reg idx)
#pragma unroll
        for (int ic = 0; ic < 32; ++ic) {
            float ov = osh[ic][tl];
            const float4 w4 = *(const float4*)(wl + 4096 + ic * 32 + oc0);  // scalar
            racc[0] += w4.x * ov;
            racc[1] += w4.y * ov;
            racc[2] += w4.z * ov;
            racc[3] += w4.w * ov;
        }
#pragma unroll
        for (int j = 0; j < 4; ++j)
            res_out[((size_t)b * 32 + oc0 + j) * Lc + t] = racc[j];
    }
}

// ============================================================
// weight packs (fp32 -> bf16, [M][K] row-major)
// ============================================================
__global__ void pack_w1(const float* __restrict__ sw, __hip_bfloat16* __restrict__ d)
{
    int idx = blockIdx.x * 256 + threadIdx.x;
    if (idx >= SCc * KTOT) return;
    int m = idx / KTOT, k = idx % KTOT;
    int i = k >> 5, c = k & 31;
    d[idx] = __float2bfloat16(sw[((size_t)i * SCc + m) * DCc + c]);
}

__global__ void pack_plain(const float* __restrict__ s, __hip_bfloat16* __restrict__ d, int n)
{
    int idx = blockIdx.x * 256 + threadIdx.x;
    if (idx < n) d[idx] = __float2bfloat16(s[idx]);
}

// ============================================================
// bf16 MFMA GEMM: Y[t][m] = sum_k X[t][k] * W[m][k]  (+bias, relu)
// Staging via global_load_lds width=16 (linear LDS dest,
// inverse-swizzled per-lane global source; swizzled read side).
// ============================================================
template <bool RELU_OUT, bool OUT_BF16>
__global__ __launch_bounds__(256) void gemm_mfma(
    const __hip_bfloat16* __restrict__ X,
    const __hip_bfloat16* __restrict__ W,
    const float* __restrict__ bias,
    void* __restrict__ Y,
    int M, int K)
{
    __shared__ i32x4 Xs[128 * 8];
    __shared__ i32x4 Ws[128 * 8];

    int tid = threadIdx.x;
    int m0  = blockIdx.x * 128;
    int by  = blockIdx.y;
    int b   = by / TTILES;
    int t0  = (by % TTILES) * 128;

    int lane = tid & 63, wid = tid >> 6;
    int wy = wid >> 1, wx = wid & 1;
    int r15 = lane & 15, q = lane >> 4;

    // gld_lds staging geometry
    int subrow = lane >> 3;             // 0..7
    int g      = (lane & 7) ^ subrow;   // granule, fixed per lane
    const __hip_bfloat16* xp[4];
    const __hip_bfloat16* wp[4];
#pragma unroll
    for (int i = 0; i < 4; ++i) {
        int r = wid * 32 + i * 8 + subrow;
        int xrow = t0 + r; if (xrow > TGT - 1) xrow = TGT - 1;
        xp[i] = X + ((size_t)(b * TGT + xrow)) * K + g * 8;
        wp[i] = W + ((size_t)(m0 + r)) * K + g * 8;
    }

    f32x4 acc[4][4] = {};

    const int nkt = K >> 6;
    for (int kt = 0; kt < nkt; ++kt) {
        __syncthreads();   // prev tile fully consumed
#pragma unroll
        for (int i = 0; i < 4; ++i) {
            __builtin_amdgcn_global_load_lds((as1v)(void*)xp[i],
                (as3v)(void*)&Xs[(wid * 4 + i) * 64], 16, 0, 0);
            __builtin_amdgcn_global_load_lds((as1v)(void*)wp[i],
                (as3v)(void*)&Ws[(wid * 4 + i) * 64], 16, 0, 0);
            xp[i] += 64;
            wp[i] += 64;
        }
        __syncthreads();   // drains vmcnt(0) -> tile ready

        const bf16x8* Xv = (const bf16x8*)Xs;
        const bf16x8* Wv = (const bf16x8*)Ws;
#pragma unroll
        for (int kk = 0; kk < 2; ++kk) {
            int sg = (kk * 4 + q) ^ (r15 & 7);
            bf16x8 af[4], bw[4];
#pragma unroll
            for (int ft = 0; ft < 4; ++ft)
                af[ft] = Xv[(wy * 64 + ft * 16 + r15) * 8 + sg];
#pragma unroll
            for (int fj = 0; fj < 4; ++fj)
                bw[fj] = Wv[(wx * 64 + fj * 16 + r15) * 8 + sg];
#pragma unroll
            for (int ft = 0; ft < 4; ++ft)
#pragma unroll
                for (int fj = 0; fj < 4; ++fj)
                    acc[ft][fj] = __builtin_amdgcn_mfma_f32_16x16x32_bf16(
                        af[ft], bw[fj], acc[ft][fj], 0, 0, 0);
        }
    }

#pragma unroll
    for (int ft = 0; ft < 4; ++ft) {
#pragma unroll
        for (int r = 0; r < 4; ++r) {
            int t = t0 + wy * 64 + ft * 16 + q * 4 + r;
            if (t < TGT) {
                size_t rowoff = ((size_t)(b * TGT + t)) * M;
#pragma unroll
                for (int fj = 0; fj < 4; ++fj) {
                    int m = m0 + wx * 64 + fj * 16 + r15;
                    float v = acc[ft][fj][r];
                    if (bias) v += bias[m];
                    if (RELU_OUT) v = fmaxf(v, 0.f);
                    if (OUT_BF16)
                        ((__hip_bfloat16*)Y)[rowoff + m] = __float2bfloat16(v);
                    else
                        ((float*)Y)[rowoff + m] = v;
                }
            }
        }
    }
}

// ============================================================
extern "C" void kernel_launch(void* const* d_in, const int* in_sizes, int n_in,
                              void* d_out, int out_size, void* d_ws, size_t ws_size,
                              hipStream_t stream)
{
    const float* inputs   = (const float*)d_in[0];
    const float* cond     = (const float*)d_in[1];
    const float* input_w  = (const float*)d_in[2];
    const float* filter_w = (const float*)d_in[3];
    const float* gate_w   = (const float*)d_in[4];
    const float* res_w    = (const float*)d_in[5];
    const float* split_w  = (const float*)d_in[6];
    const float* gcf_w    = (const float*)d_in[7];
    const float* gcs_w    = (const float*)d_in[8];
    const float* f1_w     = (const float*)d_in[9];
    const float* f1_b     = (const float*)d_in[10];
    const float* f2_w     = (const float*)d_in[11];
    const float* f2_b     = (const float*)d_in[12];
    float* out = (float*)d_out;

    char* wsb = (char*)d_ws;
    const size_t RES_B   = (size_t)Bc * RCc * Lc * 4;        // 2 MB each
    const size_t OUTS_B  = (size_t)Bc * TGT * KTOT * 2;      // 15.7 MB
    const size_t FIN_B   = (size_t)Bc * TGT * SCc * 2;       // 25.2 MB
    const size_t H1_B    = (size_t)Bc * TGT * ECc * 2;       // 12.6 MB
    const size_t W1_B    = (size_t)SCc * KTOT * 2;
    const size_t W2_B    = (size_t)ECc * SCc * 2;
    const size_t W3_B    = (size_t)OCc * ECc * 2;
    const size_t WL_B    = (size_t)NL * 5120 * 4;            // 1.6 MB

    float* res0              = (float*)wsb;                   size_t off = RES_B;
    float* res1              = (float*)(wsb + off);           off += RES_B;
    __hip_bfloat16* outsT    = (__hip_bfloat16*)(wsb + off);  off += OUTS_B;
    __hip_bfloat16* finalT   = (__hip_bfloat16*)(wsb + off);  off += FIN_B;
    __hip_bfloat16* h1T      = (__hip_bfloat16*)(wsb + off);  off += H1_B;
    __hip_bfloat16* Wp1      = (__hip_bfloat16*)(wsb + off);  off += W1_B;
    __hip_bfloat16* Wp2      = (__hip_bfloat16*)(wsb + off);  off += W2_B;
    __hip_bfloat16* Wp3      = (__hip_bfloat16*)(wsb + off);  off += W3_B;
    float* wlpack            = (float*)(wsb + off);           off += WL_B;

    // weight packs (independent of activations)
    pack_w1<<<(SCc * KTOT + 255) / 256, 256, 0, stream>>>(split_w, Wp1);
    pack_plain<<<(ECc * SCc + 255) / 256, 256, 0, stream>>>(f1_w, Wp2, ECc * SCc);
    pack_plain<<<(OCc * ECc + 255) / 256, 256, 0, stream>>>(f2_w, Wp3, OCc * ECc);
    pack_layerw<<<(NL * 5120 + 255) / 256, 256, 0, stream>>>(filter_w, gate_w, res_w, wlpack);

    input_conv<<<dim3(Lc / 64, Bc), 256, 0, stream>>>(inputs, input_w, res0);

    float* rin = res0;
    float* rout = res1;
    for (int i = 0; i < NL; ++i) {
        int d = 1 << (i % 10);
        const float* wl = wlpack + (size_t)i * 5120;
        if (i + 1 < NL)
            layer_v4<false><<<dim3(Lc / 64, Bc), 512, 0, stream>>>(
                rin, rout, outsT, wl, cond, gcf_w + i * 5, gcs_w + i * 5, d, i);
        else
            layer_v4<true><<<dim3(Lc / 64, Bc), 512, 0, stream>>>(
                rin, rout, outsT, wl, cond, gcf_w + i * 5, gcs_w + i * 5, d, i);
        float* tmp = rin; rin = rout; rout = tmp;
    }

    // G1: finalT = relu( outsT(12292x640) @ Wp1^T )   -> bf16 [t][1024]
    gemm_mfma<true, true><<<dim3(SCc / 128, Bc * TTILES), 256, 0, stream>>>(
        outsT, Wp1, nullptr, finalT, SCc, KTOT);

    // G2: h1T = relu( finalT @ Wp2^T + f1_b )         -> bf16 [t][512]
    gemm_mfma<true, true><<<dim3(ECc / 128, Bc * TTILES), 256, 0, stream>>>(
        finalT, Wp2, f1_b, h1T, ECc, SCc);

    // G3: out = h1T @ Wp3^T + f2_b                    -> fp32 [t][256] (final layout)
    gemm_mfma<false, false><<<dim3(OCc / 128, Bc * TTILES), 256, 0, stream>>>(
        h1T, Wp3, f2_b, out, OCc, ECc);
}

// Round 7
// 305.528 us; speedup vs baseline: 1.4969x; 1.4969x over previous
//
#include <hip/hip_runtime.h>
#include <hip/hip_bf16.h>
#include <cstddef>

// ---- problem constants ----
#define Bc   2
#define Lc   8192
#define TGT  6146          // L - RF, RF = 2046
#define NL   20            // layers
#define RCc  32
#define DCc  32
#define SCc  1024
#define ECc  512
#define OCc  256
#define KTOT (NL * DCc)    // 640
#define TTILES 49          // ceil(TGT/128)

typedef __attribute__((ext_vector_type(4))) float f32x4;
typedef __attribute__((ext_vector_type(8))) short bf16x8;
typedef __attribute__((ext_vector_type(4))) int i32x4;
typedef __attribute__((ext_vector_type(2))) int i32x2;

typedef __attribute__((address_space(1))) void* as1v;
typedef __attribute__((address_space(3))) void* as3v;

// ============================================================
// K0: input 1x1 conv  (B,256,L) x (32,256) -> res (B,32,L)
// ============================================================
__global__ __launch_bounds__(256) void input_conv(
    const float* __restrict__ x,   // [B][256][L]
    const float* __restrict__ w,   // [32][256]
    float* __restrict__ res_out)   // [B][32][L]
{
    __shared__ float ws[32][256];
    __shared__ float xs[64][64];
    int tid = threadIdx.x;
    int b   = blockIdx.y;
    int t0  = blockIdx.x * 64;

    for (int idx = tid; idx < 32 * 256; idx += 256)
        ws[idx >> 8][idx & 255] = w[idx];

    int tl = tid & 63, qq = tid >> 6, oc0 = qq * 8;
    float acc[8] = {};

    for (int icc = 0; icc < 4; ++icc) {
        __syncthreads();
        for (int idx = tid; idx < 64 * 64; idx += 256) {
            int icl = idx >> 6, tll = idx & 63;
            xs[icl][tll] = x[((size_t)b * 256 + icc * 64 + icl) * Lc + t0 + tll];
        }
        __syncthreads();
        for (int icl = 0; icl < 64; icl += 4) {
            float x0 = xs[icl][tl], x1 = xs[icl + 1][tl];
            float x2 = xs[icl + 2][tl], x3 = xs[icl + 3][tl];
#pragma unroll
            for (int j = 0; j < 8; ++j) {
                const float4 w4 = *(const float4*)&ws[oc0 + j][icc * 64 + icl];
                acc[j] += w4.x * x0 + w4.y * x1 + w4.z * x2 + w4.w * x3;
            }
        }
    }
#pragma unroll
    for (int j = 0; j < 8; ++j)
        res_out[((size_t)b * 32 + oc0 + j) * Lc + t0 + tl] = acc[j];
}

// ============================================================
// layer weight pre-pack, bf16 + granule-swizzled (slot = g ^ (m&7)).
// wfgp[li][m 0..63][64]: m<32 -> F row, m>=32 -> G row; k<32 tap0(x[t-d]), k>=32 tap1(x[t]).
// wrp[li][m 0..31][64]: k<32 = resw[m][k], rest 0.
// ============================================================
__global__ void pack_wfgr(const float* __restrict__ filt,
                          const float* __restrict__ gate,
                          const float* __restrict__ resw,
                          __hip_bfloat16* __restrict__ wfgp,
                          __hip_bfloat16* __restrict__ wrp)
{
    int idx = blockIdx.x * 256 + threadIdx.x;
    if (idx < NL * 64 * 64) {
        int li = idx / 4096, r = idx % 4096;
        int m = r >> 6, k = r & 63;
        int tap = k >> 5, ic = k & 31;
        float v = (m < 32) ? filt[(size_t)li * 2048 + (m * 32 + ic) * 2 + tap]
                           : gate[(size_t)li * 2048 + ((m - 32) * 32 + ic) * 2 + tap];
        int slot = (k >> 3) ^ (m & 7);
        wfgp[((size_t)li * 64 + m) * 64 + slot * 8 + (k & 7)] = __float2bfloat16(v);
    }
    if (idx < NL * 32 * 64) {
        int li = idx / 2048, r = idx % 2048;
        int m = r >> 6, k = r & 63;
        float v = (k < 32) ? resw[(size_t)li * 1024 + m * 32 + k] : 0.f;
        int slot = (k >> 3) ^ (m & 7);
        wrp[((size_t)li * 32 + m) * 64 + slot * 8 + (k & 7)] = __float2bfloat16(v);
    }
}

// ============================================================
// per-layer MFMA kernel: 256 thr (4 waves), 64-t tile.
// [F;G](64m x 64t) = Wfg @ [xm;x0]; o = tanh(F+gf)*sig(G+gg);
// res_out = res_in + Wr @ o  (second MFMA, K=32).
// Residual stream stays fp32 in global; o/x/weights bf16.
// ============================================================
template <bool SKIPRES>
__global__ __launch_bounds__(256) void layer_mfma(
    const float* __restrict__ res_in,   // [B][32][L]
    float* __restrict__ res_out,        // [B][32][L]
    __hip_bfloat16* __restrict__ outsT, // [B*TGT][640]
    const __hip_bfloat16* __restrict__ wfg,  // [64][64] this layer (pre-swizzled)
    const __hip_bfloat16* __restrict__ wr,   // [32][64] this layer (pre-swizzled)
    const float* __restrict__ cond,
    const float* __restrict__ gcf,
    const float* __restrict__ gcs,
    int dil, int li)
{
    __shared__ __align__(16) i32x4 Xs[64 * 8];        // 8 KB  [t][slot]
    __shared__ __align__(16) i32x4 Wf[64 * 8];        // 8 KB  [m][slot]
    __shared__ __align__(16) i32x4 Wrs[32 * 8];       // 4 KB
    __shared__ __align__(16) unsigned short Os[64 * 64];  // 8 KB [t][slot*8+e]

    int tid  = threadIdx.x;
    int b    = blockIdx.y;
    int t0   = blockIdx.x * 64;
    int lane = tid & 63, wid = tid >> 6;
    int r15  = lane & 15, q = lane >> 4;
    int wt0  = wid * 16;

    // ---- weight staging: linear copies via global_load_lds (pre-swizzled src) ----
#pragma unroll
    for (int c = 0; c < 2; ++c)
        __builtin_amdgcn_global_load_lds(
            (as1v)(void*)((const i32x4*)wfg + (wid * 2 + c) * 64 + lane),
            (as3v)(void*)&Wf[(wid * 2 + c) * 64], 16, 0, 0);
    if (!SKIPRES)
        __builtin_amdgcn_global_load_lds(
            (as1v)(void*)((const i32x4*)wr + wid * 64 + lane),
            (as3v)(void*)&Wrs[wid * 64], 16, 0, 0);

    // ---- X staging: thread -> (t = tid>>2, two granules) ----
    {
        int tloc = tid >> 2;
        int tg   = t0 + tloc;
        const float* rb = res_in + (size_t)b * 32 * Lc;
#pragma unroll
        for (int gi = 0; gi < 2; ++gi) {
            int g = (tid & 3) * 2 + gi;
            union { i32x4 v; __hip_bfloat16 h[8]; } u;
#pragma unroll
            for (int j = 0; j < 8; ++j) {
                int k = g * 8 + j;
                float v;
                if (k < 32) v = (tg >= dil) ? rb[(size_t)k * Lc + tg - dil] : 0.f;
                else        v = rb[(size_t)(k - 32) * Lc + tg];
                u.h[j] = __float2bfloat16(v);
            }
            Xs[tloc * 8 + (g ^ (tloc & 7))] = u.v;
        }
    }

    float gf = gcf[0] * cond[b * 5 + 0] + gcf[1] * cond[b * 5 + 1] +
               gcf[2] * cond[b * 5 + 2] + gcf[3] * cond[b * 5 + 3] +
               gcf[4] * cond[b * 5 + 4];
    float gg = gcs[0] * cond[b * 5 + 0] + gcs[1] * cond[b * 5 + 1] +
               gcs[2] * cond[b * 5 + 2] + gcs[3] * cond[b * 5 + 3] +
               gcs[4] * cond[b * 5 + 4];

    __syncthreads();   // staging complete (drains vmcnt + lgkm)

    // ---- f/g conv MFMA: per wave 16t x 64m, K=64 ----
    const bf16x8* Xv = (const bf16x8*)Xs;
    const bf16x8* Wv = (const bf16x8*)Wf;
    f32x4 acc[4] = {};
#pragma unroll
    for (int kk = 0; kk < 2; ++kk) {
        int sg = (kk * 4 + q) ^ (r15 & 7);
        bf16x8 af = Xv[(wt0 + r15) * 8 + sg];
#pragma unroll
        for (int fj = 0; fj < 4; ++fj)
            acc[fj] = __builtin_amdgcn_mfma_f32_16x16x32_bf16(
                af, Wv[(fj * 16 + r15) * 8 + sg], acc[fj], 0, 0, 0);
    }

    // ---- activation; o -> Os (LDS) + skip store (global bf16) ----
#pragma unroll
    for (int fj = 0; fj < 2; ++fj) {
#pragma unroll
        for (int r = 0; r < 4; ++r) {
            float F = acc[fj][r] + gf;
            float G = acc[fj + 2][r] + gg;
            float th = 1.f - 2.f / (__expf(2.f * F) + 1.f);
            float sg = 1.f / (1.f + __expf(-G));
            float o  = th * sg;
            int tl2 = wt0 + q * 4 + r;
            int ic  = fj * 16 + r15;
            __hip_bfloat16 ob = __float2bfloat16(o);
            if (!SKIPRES) {
                int gsl = (ic >> 3) ^ (tl2 & 7);
                Os[tl2 * 64 + gsl * 8 + (ic & 7)] = *(unsigned short*)&ob;
            }
            int tgo = t0 + tl2;
            if (tgo >= Lc - TGT)
                outsT[((size_t)(b * TGT + tgo - (Lc - TGT))) * KTOT + li * 32 + ic] = ob;
        }
    }

    if (!SKIPRES) {
        __syncthreads();   // Os complete (cheap; guarantees ds_write->ds_read order)
        const bf16x8* Ov  = (const bf16x8*)Os;
        const bf16x8* Rv  = (const bf16x8*)Wrs;
        int sg = q ^ (r15 & 7);
        bf16x8 ao = Ov[(wt0 + r15) * 8 + sg];
        f32x4 racc[2] = {};
#pragma unroll
        for (int fj = 0; fj < 2; ++fj)
            racc[fj] = __builtin_amdgcn_mfma_f32_16x16x32_bf16(
                ao, Rv[(fj * 16 + r15) * 8 + sg], racc[fj], 0, 0, 0);
#pragma unroll
        for (int fj = 0; fj < 2; ++fj) {
#pragma unroll
            for (int r = 0; r < 4; ++r) {
                int oc  = fj * 16 + r15;
                int tgl = t0 + wt0 + q * 4 + r;
                size_t a = ((size_t)(b * 32 + oc)) * Lc + tgl;
                res_out[a] = res_in[a] + racc[fj][r];
            }
        }
    }
}

// ============================================================
// weight packs (fp32 -> bf16, [M][K] row-major)
// ============================================================
__global__ void pack_w1(const float* __restrict__ sw, __hip_bfloat16* __restrict__ d)
{
    int idx = blockIdx.x * 256 + threadIdx.x;
    if (idx >= SCc * KTOT) return;
    int m = idx / KTOT, k = idx % KTOT;
    int i = k >> 5, c = k & 31;
    d[idx] = __float2bfloat16(sw[((size_t)i * SCc + m) * DCc + c]);
}

__global__ void pack_plain(const float* __restrict__ s, __hip_bfloat16* __restrict__ d, int n)
{
    int idx = blockIdx.x * 256 + threadIdx.x;
    if (idx < n) d[idx] = __float2bfloat16(s[idx]);
}

// ============================================================
// bf16 MFMA GEMM: Y[t][m] = sum_k X[t][k] * W[m][k]  (+bias, relu)
// Staging via global_load_lds width=16 (linear LDS dest,
// inverse-swizzled per-lane global source; swizzled read side).
// ============================================================
template <bool RELU_OUT, bool OUT_BF16>
__global__ __launch_bounds__(256) void gemm_mfma(
    const __hip_bfloat16* __restrict__ X,
    const __hip_bfloat16* __restrict__ W,
    const float* __restrict__ bias,
    void* __restrict__ Y,
    int M, int K)
{
    __shared__ i32x4 Xs[128 * 8];
    __shared__ i32x4 Ws[128 * 8];

    int tid = threadIdx.x;
    int m0  = blockIdx.x * 128;
    int by  = blockIdx.y;
    int b   = by / TTILES;
    int t0  = (by % TTILES) * 128;

    int lane = tid & 63, wid = tid >> 6;
    int wy = wid >> 1, wx = wid & 1;
    int r15 = lane & 15, q = lane >> 4;

    int subrow = lane >> 3;             // 0..7
    int g      = (lane & 7) ^ subrow;   // granule, fixed per lane
    const __hip_bfloat16* xp[4];
    const __hip_bfloat16* wp[4];
#pragma unroll
    for (int i = 0; i < 4; ++i) {
        int r = wid * 32 + i * 8 + subrow;
        int xrow = t0 + r; if (xrow > TGT - 1) xrow = TGT - 1;
        xp[i] = X + ((size_t)(b * TGT + xrow)) * K + g * 8;
        wp[i] = W + ((size_t)(m0 + r)) * K + g * 8;
    }

    f32x4 acc[4][4] = {};

    const int nkt = K >> 6;
    for (int kt = 0; kt < nkt; ++kt) {
        __syncthreads();
#pragma unroll
        for (int i = 0; i < 4; ++i) {
            __builtin_amdgcn_global_load_lds((as1v)(void*)xp[i],
                (as3v)(void*)&Xs[(wid * 4 + i) * 64], 16, 0, 0);
            __builtin_amdgcn_global_load_lds((as1v)(void*)wp[i],
                (as3v)(void*)&Ws[(wid * 4 + i) * 64], 16, 0, 0);
            xp[i] += 64;
            wp[i] += 64;
        }
        __syncthreads();

        const bf16x8* Xv = (const bf16x8*)Xs;
        const bf16x8* Wv = (const bf16x8*)Ws;
#pragma unroll
        for (int kk = 0; kk < 2; ++kk) {
            int sg = (kk * 4 + q) ^ (r15 & 7);
            bf16x8 af[4], bw[4];
#pragma unroll
            for (int ft = 0; ft < 4; ++ft)
                af[ft] = Xv[(wy * 64 + ft * 16 + r15) * 8 + sg];
#pragma unroll
            for (int fj = 0; fj < 4; ++fj)
                bw[fj] = Wv[(wx * 64 + fj * 16 + r15) * 8 + sg];
#pragma unroll
            for (int ft = 0; ft < 4; ++ft)
#pragma unroll
                for (int fj = 0; fj < 4; ++fj)
                    acc[ft][fj] = __builtin_amdgcn_mfma_f32_16x16x32_bf16(
                        af[ft], bw[fj], acc[ft][fj], 0, 0, 0);
        }
    }

#pragma unroll
    for (int ft = 0; ft < 4; ++ft) {
#pragma unroll
        for (int r = 0; r < 4; ++r) {
            int t = t0 + wy * 64 + ft * 16 + q * 4 + r;
            if (t < TGT) {
                size_t rowoff = ((size_t)(b * TGT + t)) * M;
#pragma unroll
                for (int fj = 0; fj < 4; ++fj) {
                    int m = m0 + wx * 64 + fj * 16 + r15;
                    float v = acc[ft][fj][r];
                    if (bias) v += bias[m];
                    if (RELU_OUT) v = fmaxf(v, 0.f);
                    if (OUT_BF16)
                        ((__hip_bfloat16*)Y)[rowoff + m] = __float2bfloat16(v);
                    else
                        ((float*)Y)[rowoff + m] = v;
                }
            }
        }
    }
}

// ============================================================
extern "C" void kernel_launch(void* const* d_in, const int* in_sizes, int n_in,
                              void* d_out, int out_size, void* d_ws, size_t ws_size,
                              hipStream_t stream)
{
    const float* inputs   = (const float*)d_in[0];
    const float* cond     = (const float*)d_in[1];
    const float* input_w  = (const float*)d_in[2];
    const float* filter_w = (const float*)d_in[3];
    const float* gate_w   = (const float*)d_in[4];
    const float* res_w    = (const float*)d_in[5];
    const float* split_w  = (const float*)d_in[6];
    const float* gcf_w    = (const float*)d_in[7];
    const float* gcs_w    = (const float*)d_in[8];
    const float* f1_w     = (const float*)d_in[9];
    const float* f1_b     = (const float*)d_in[10];
    const float* f2_w     = (const float*)d_in[11];
    const float* f2_b     = (const float*)d_in[12];
    float* out = (float*)d_out;

    char* wsb = (char*)d_ws;
    const size_t RES_B   = (size_t)Bc * RCc * Lc * 4;        // 2 MB each
    const size_t OUTS_B  = (size_t)Bc * TGT * KTOT * 2;      // 15.7 MB
    const size_t FIN_B   = (size_t)Bc * TGT * SCc * 2;       // 25.2 MB
    const size_t H1_B    = (size_t)Bc * TGT * ECc * 2;       // 12.6 MB
    const size_t W1_B    = (size_t)SCc * KTOT * 2;
    const size_t W2_B    = (size_t)ECc * SCc * 2;
    const size_t W3_B    = (size_t)OCc * ECc * 2;
    const size_t WFG_B   = (size_t)NL * 64 * 64 * 2;         // 160 KB
    const size_t WR_B    = (size_t)NL * 32 * 64 * 2;         // 80 KB

    float* res0              = (float*)wsb;                   size_t off = RES_B;
    float* res1              = (float*)(wsb + off);           off += RES_B;
    __hip_bfloat16* outsT    = (__hip_bfloat16*)(wsb + off);  off += OUTS_B;
    __hip_bfloat16* finalT   = (__hip_bfloat16*)(wsb + off);  off += FIN_B;
    __hip_bfloat16* h1T      = (__hip_bfloat16*)(wsb + off);  off += H1_B;
    __hip_bfloat16* Wp1      = (__hip_bfloat16*)(wsb + off);  off += W1_B;
    __hip_bfloat16* Wp2      = (__hip_bfloat16*)(wsb + off);  off += W2_B;
    __hip_bfloat16* Wp3      = (__hip_bfloat16*)(wsb + off);  off += W3_B;
    __hip_bfloat16* wfgp     = (__hip_bfloat16*)(wsb + off);  off += WFG_B;
    __hip_bfloat16* wrp      = (__hip_bfloat16*)(wsb + off);  off += WR_B;

    // weight packs (independent of activations)
    pack_w1<<<(SCc * KTOT + 255) / 256, 256, 0, stream>>>(split_w, Wp1);
    pack_plain<<<(ECc * SCc + 255) / 256, 256, 0, stream>>>(f1_w, Wp2, ECc * SCc);
    pack_plain<<<(OCc * ECc + 255) / 256, 256, 0, stream>>>(f2_w, Wp3, OCc * ECc);
    pack_wfgr<<<(NL * 64 * 64 + 255) / 256, 256, 0, stream>>>(
        filter_w, gate_w, res_w, wfgp, wrp);

    input_conv<<<dim3(Lc / 64, Bc), 256, 0, stream>>>(inputs, input_w, res0);

    float* rin = res0;
    float* rout = res1;
    for (int i = 0; i < NL; ++i) {
        int d = 1 << (i % 10);
        const __hip_bfloat16* wfg = wfgp + (size_t)i * 64 * 64;
        const __hip_bfloat16* wr  = wrp  + (size_t)i * 32 * 64;
        if (i + 1 < NL)
            layer_mfma<false><<<dim3(Lc / 64, Bc), 256, 0, stream>>>(
                rin, rout, outsT, wfg, wr, cond, gcf_w + i * 5, gcs_w + i * 5, d, i);
        else
            layer_mfma<true><<<dim3(Lc / 64, Bc), 256, 0, stream>>>(
                rin, rout, outsT, wfg, wr, cond, gcf_w + i * 5, gcs_w + i * 5, d, i);
        float* tmp = rin; rin = rout; rout = tmp;
    }

    // G1: finalT = relu( outsT(12292x640) @ Wp1^T )   -> bf16 [t][1024]
    gemm_mfma<true, true><<<dim3(SCc / 128, Bc * TTILES), 256, 0, stream>>>(
        outsT, Wp1, nullptr, finalT, SCc, KTOT);

    // G2: h1T = relu( finalT @ Wp2^T + f1_b )         -> bf16 [t][512]
    gemm_mfma<true, true><<<dim3(ECc / 128, Bc * TTILES), 256, 0, stream>>>(
        finalT, Wp2, f1_b, h1T, ECc, SCc);

    // G3: out = h1T @ Wp3^T + f2_b                    -> fp32 [t][256] (final layout)
    gemm_mfma<false, false><<<dim3(OCc / 128, Bc * TTILES), 256, 0, stream>>>(
        h1T, Wp3, f2_b, out, OCc, ECc);
}

// Round 8
// 298.344 us; speedup vs baseline: 1.5330x; 1.0241x over previous
//
#include <hip/hip_runtime.h>
#include <hip/hip_bf16.h>
#include <cstddef>

// ---- problem constants ----
#define Bc   2
#define Lc   8192
#define TGT  6146          // L - RF, RF = 2046
#define NL   20            // layers
#define RCc  32
#define DCc  32
#define SCc  1024
#define ECc  512
#define OCc  256
#define KTOT (NL * DCc)    // 640
#define TTILES 49          // ceil(TGT/128)

typedef __attribute__((ext_vector_type(4))) float f32x4;
typedef __attribute__((ext_vector_type(8))) short bf16x8;
typedef __attribute__((ext_vector_type(4))) int i32x4;
typedef __attribute__((ext_vector_type(2))) int i32x2;

typedef __attribute__((address_space(1))) void* as1v;
typedef __attribute__((address_space(3))) void* as3v;

// ============================================================
// K0: input 1x1 conv  (B,256,L) x (32,256) -> res (B,32,L)
// ============================================================
__global__ __launch_bounds__(256) void input_conv(
    const float* __restrict__ x,   // [B][256][L]
    const float* __restrict__ w,   // [32][256]
    float* __restrict__ res_out)   // [B][32][L]
{
    __shared__ float ws[32][256];
    __shared__ float xs[64][64];
    int tid = threadIdx.x;
    int b   = blockIdx.y;
    int t0  = blockIdx.x * 64;

    for (int idx = tid; idx < 32 * 256; idx += 256)
        ws[idx >> 8][idx & 255] = w[idx];

    int tl = tid & 63, qq = tid >> 6, oc0 = qq * 8;
    float acc[8] = {};

    for (int icc = 0; icc < 4; ++icc) {
        __syncthreads();
        for (int idx = tid; idx < 64 * 64; idx += 256) {
            int icl = idx >> 6, tll = idx & 63;
            xs[icl][tll] = x[((size_t)b * 256 + icc * 64 + icl) * Lc + t0 + tll];
        }
        __syncthreads();
        for (int icl = 0; icl < 64; icl += 4) {
            float x0 = xs[icl][tl], x1 = xs[icl + 1][tl];
            float x2 = xs[icl + 2][tl], x3 = xs[icl + 3][tl];
#pragma unroll
            for (int j = 0; j < 8; ++j) {
                const float4 w4 = *(const float4*)&ws[oc0 + j][icc * 64 + icl];
                acc[j] += w4.x * x0 + w4.y * x1 + w4.z * x2 + w4.w * x3;
            }
        }
    }
#pragma unroll
    for (int j = 0; j < 8; ++j)
        res_out[((size_t)b * 32 + oc0 + j) * Lc + t0 + tl] = acc[j];
}

// ============================================================
// layer weight pre-pack, bf16 + granule-swizzled (slot = g ^ (m&7)).
// ============================================================
__global__ void pack_wfgr(const float* __restrict__ filt,
                          const float* __restrict__ gate,
                          const float* __restrict__ resw,
                          __hip_bfloat16* __restrict__ wfgp,
                          __hip_bfloat16* __restrict__ wrp)
{
    int idx = blockIdx.x * 256 + threadIdx.x;
    if (idx < NL * 64 * 64) {
        int li = idx / 4096, r = idx % 4096;
        int m = r >> 6, k = r & 63;
        int tap = k >> 5, ic = k & 31;
        float v = (m < 32) ? filt[(size_t)li * 2048 + (m * 32 + ic) * 2 + tap]
                           : gate[(size_t)li * 2048 + ((m - 32) * 32 + ic) * 2 + tap];
        int slot = (k >> 3) ^ (m & 7);
        wfgp[((size_t)li * 64 + m) * 64 + slot * 8 + (k & 7)] = __float2bfloat16(v);
    }
    if (idx < NL * 32 * 64) {
        int li = idx / 2048, r = idx % 2048;
        int m = r >> 6, k = r & 63;
        float v = (k < 32) ? resw[(size_t)li * 1024 + m * 32 + k] : 0.f;
        int slot = (k >> 3) ^ (m & 7);
        wrp[((size_t)li * 32 + m) * 64 + slot * 8 + (k & 7)] = __float2bfloat16(v);
    }
}

// ============================================================
// per-layer MFMA kernel: 256 thr (4 waves), 64-t tile.
// [F;G](64m x 64t) = Wfg @ [xm;x0]; o = tanh(F+gf)*sig(G+gg);
// res_out = res_in + Wr @ o  (second MFMA, K=32).
// Residual epilogue routed through LDS -> coalesced float4 I/O.
// ============================================================
template <bool SKIPRES>
__global__ __launch_bounds__(256) void layer_mfma(
    const float* __restrict__ res_in,   // [B][32][L]
    float* __restrict__ res_out,        // [B][32][L]
    __hip_bfloat16* __restrict__ outsT, // [B*TGT][640]
    const __hip_bfloat16* __restrict__ wfg,  // [64][64] (pre-swizzled)
    const __hip_bfloat16* __restrict__ wr,   // [32][64] (pre-swizzled)
    const float* __restrict__ cond,
    const float* __restrict__ gcf,
    const float* __restrict__ gcs,
    int dil, int li)
{
    __shared__ __align__(16) i32x4 Xs[64 * 8];            // 8 KB  [t][slot]
    __shared__ __align__(16) i32x4 Wf[64 * 8];            // 8 KB  [m][slot]
    __shared__ __align__(16) i32x4 Wrs[32 * 8];           // 4 KB
    __shared__ __align__(16) unsigned short Os[64 * 64];  // 8 KB  [t][slot*8+e]
    __shared__ float Rxf[32][65];                         // 8.3 KB

    int tid  = threadIdx.x;
    int b    = blockIdx.y;
    int t0   = blockIdx.x * 64;
    int lane = tid & 63, wid = tid >> 6;
    int r15  = lane & 15, q = lane >> 4;
    int wt0  = wid * 16;

    // ---- weight staging: linear copies via global_load_lds (pre-swizzled src) ----
#pragma unroll
    for (int c = 0; c < 2; ++c)
        __builtin_amdgcn_global_load_lds(
            (as1v)(void*)((const i32x4*)wfg + (wid * 2 + c) * 64 + lane),
            (as3v)(void*)&Wf[(wid * 2 + c) * 64], 16, 0, 0);
    if (!SKIPRES)
        __builtin_amdgcn_global_load_lds(
            (as1v)(void*)((const i32x4*)wr + wid * 64 + lane),
            (as3v)(void*)&Wrs[wid * 64], 16, 0, 0);

    // ---- X staging: thread -> (t = tid>>2, two granules) ----
    {
        int tloc = tid >> 2;
        int tg   = t0 + tloc;
        const float* rb = res_in + (size_t)b * 32 * Lc;
#pragma unroll
        for (int gi = 0; gi < 2; ++gi) {
            int g = (tid & 3) * 2 + gi;
            union { i32x4 v; __hip_bfloat16 h[8]; } u;
#pragma unroll
            for (int j = 0; j < 8; ++j) {
                int k = g * 8 + j;
                float v;
                if (k < 32) v = (tg >= dil) ? rb[(size_t)k * Lc + tg - dil] : 0.f;
                else        v = rb[(size_t)(k - 32) * Lc + tg];
                u.h[j] = __float2bfloat16(v);
            }
            Xs[tloc * 8 + (g ^ (tloc & 7))] = u.v;
        }
    }

    float gf = gcf[0] * cond[b * 5 + 0] + gcf[1] * cond[b * 5 + 1] +
               gcf[2] * cond[b * 5 + 2] + gcf[3] * cond[b * 5 + 3] +
               gcf[4] * cond[b * 5 + 4];
    float gg = gcs[0] * cond[b * 5 + 0] + gcs[1] * cond[b * 5 + 1] +
               gcs[2] * cond[b * 5 + 2] + gcs[3] * cond[b * 5 + 3] +
               gcs[4] * cond[b * 5 + 4];

    __syncthreads();   // staging complete (drains vmcnt + lgkm)

    // ---- f/g conv MFMA: per wave 16t x 64m, K=64 ----
    const bf16x8* Xv = (const bf16x8*)Xs;
    const bf16x8* Wv = (const bf16x8*)Wf;
    f32x4 acc[4] = {};
#pragma unroll
    for (int kk = 0; kk < 2; ++kk) {
        int sg = (kk * 4 + q) ^ (r15 & 7);
        bf16x8 af = Xv[(wt0 + r15) * 8 + sg];
#pragma unroll
        for (int fj = 0; fj < 4; ++fj)
            acc[fj] = __builtin_amdgcn_mfma_f32_16x16x32_bf16(
                af, Wv[(fj * 16 + r15) * 8 + sg], acc[fj], 0, 0, 0);
    }

    // ---- activation; o -> Os (LDS) + skip store (global bf16) ----
#pragma unroll
    for (int fj = 0; fj < 2; ++fj) {
#pragma unroll
        for (int r = 0; r < 4; ++r) {
            float F = acc[fj][r] + gf;
            float G = acc[fj + 2][r] + gg;
            float th = 1.f - 2.f / (__expf(2.f * F) + 1.f);
            float sg = 1.f / (1.f + __expf(-G));
            float o  = th * sg;
            int tl2 = wt0 + q * 4 + r;
            int ic  = fj * 16 + r15;
            __hip_bfloat16 ob = __float2bfloat16(o);
            if (!SKIPRES) {
                int gsl = (ic >> 3) ^ (tl2 & 7);
                Os[tl2 * 64 + gsl * 8 + (ic & 7)] = *(unsigned short*)&ob;
            }
            int tgo = t0 + tl2;
            if (tgo >= Lc - TGT)
                outsT[((size_t)(b * TGT + tgo - (Lc - TGT))) * KTOT + li * 32 + ic] = ob;
        }
    }

    if (!SKIPRES) {
        __syncthreads();   // Os complete
        const bf16x8* Ov  = (const bf16x8*)Os;
        const bf16x8* Rv  = (const bf16x8*)Wrs;
        int sg = q ^ (r15 & 7);
        bf16x8 ao = Ov[(wt0 + r15) * 8 + sg];
        f32x4 racc[2] = {};
#pragma unroll
        for (int fj = 0; fj < 2; ++fj)
            racc[fj] = __builtin_amdgcn_mfma_f32_16x16x32_bf16(
                ao, Rv[(fj * 16 + r15) * 8 + sg], racc[fj], 0, 0, 0);

        // exchange through LDS for coalesced residual update
#pragma unroll
        for (int fj = 0; fj < 2; ++fj)
#pragma unroll
            for (int r = 0; r < 4; ++r)
                Rxf[fj * 16 + r15][wt0 + q * 4 + r] = racc[fj][r];
        __syncthreads();

        int row = tid >> 3, ch = tid & 7;
        size_t ga = ((size_t)(b * 32) + row) * Lc + t0 + ch * 8;
        const float4* ri = (const float4*)(res_in + ga);
        float4* ro = (float4*)(res_out + ga);
        const float* rx = &Rxf[row][ch * 8];
        float4 a0 = ri[0], a1 = ri[1];
        a0.x += rx[0]; a0.y += rx[1]; a0.z += rx[2]; a0.w += rx[3];
        a1.x += rx[4]; a1.y += rx[5]; a1.z += rx[6]; a1.w += rx[7];
        ro[0] = a0; ro[1] = a1;
    }
}

// ============================================================
// weight packs (fp32 -> bf16, [M][K] row-major)
// ============================================================
__global__ void pack_w1(const float* __restrict__ sw, __hip_bfloat16* __restrict__ d)
{
    int idx = blockIdx.x * 256 + threadIdx.x;
    if (idx >= SCc * KTOT) return;
    int m = idx / KTOT, k = idx % KTOT;
    int i = k >> 5, c = k & 31;
    d[idx] = __float2bfloat16(sw[((size_t)i * SCc + m) * DCc + c]);
}

__global__ void pack_plain(const float* __restrict__ s, __hip_bfloat16* __restrict__ d, int n)
{
    int idx = blockIdx.x * 256 + threadIdx.x;
    if (idx < n) d[idx] = __float2bfloat16(s[idx]);
}

// ============================================================
// bf16 MFMA GEMM, 2-phase double-buffered, counted vmcnt (T3+T4).
// Y[t][m] = sum_k X[t][k] * W[m][k]  (+bias, relu)
// Staging via global_load_lds width=16 (linear LDS dest,
// inverse-swizzled per-lane global source; swizzled read side).
// ============================================================
template <bool RELU_OUT, bool OUT_BF16>
__global__ __launch_bounds__(256) void gemm_mfma(
    const __hip_bfloat16* __restrict__ X,
    const __hip_bfloat16* __restrict__ W,
    const float* __restrict__ bias,
    void* __restrict__ Y,
    int M, int K)
{
    __shared__ i32x4 Xs0[128 * 8];
    __shared__ i32x4 Ws0[128 * 8];
    __shared__ i32x4 Xs1[128 * 8];
    __shared__ i32x4 Ws1[128 * 8];   // 64 KB total

    int tid = threadIdx.x;
    int m0  = blockIdx.x * 128;
    int by  = blockIdx.y;
    int b   = by / TTILES;
    int t0  = (by % TTILES) * 128;

    int lane = tid & 63, wid = tid >> 6;
    int wy = wid >> 1, wx = wid & 1;
    int r15 = lane & 15, q = lane >> 4;

    int subrow = lane >> 3;             // 0..7
    int g      = (lane & 7) ^ subrow;   // granule, fixed per lane
    const __hip_bfloat16* xp[4];
    const __hip_bfloat16* wp[4];
#pragma unroll
    for (int i = 0; i < 4; ++i) {
        int r = wid * 32 + i * 8 + subrow;
        int xrow = t0 + r; if (xrow > TGT - 1) xrow = TGT - 1;
        xp[i] = X + ((size_t)(b * TGT + xrow)) * K + g * 8;
        wp[i] = W + ((size_t)(m0 + r)) * K + g * 8;
    }

    f32x4 acc[4][4] = {};

#define STAGE(XB, WB)                                                          \
    {                                                                          \
        _Pragma("unroll")                                                      \
        for (int i = 0; i < 4; ++i) {                                          \
            __builtin_amdgcn_global_load_lds((as1v)(void*)xp[i],               \
                (as3v)(void*)&XB[(wid * 4 + i) * 64], 16, 0, 0);               \
            __builtin_amdgcn_global_load_lds((as1v)(void*)wp[i],               \
                (as3v)(void*)&WB[(wid * 4 + i) * 64], 16, 0, 0);               \
            xp[i] += 64; wp[i] += 64;                                          \
        }                                                                      \
    }

    auto compute = [&](const i32x4* Xb, const i32x4* Wb) {
        const bf16x8* Xv = (const bf16x8*)Xb;
        const bf16x8* Wv = (const bf16x8*)Wb;
#pragma unroll
        for (int kk = 0; kk < 2; ++kk) {
            int sg = (kk * 4 + q) ^ (r15 & 7);
            bf16x8 af[4], bw[4];
#pragma unroll
            for (int ft = 0; ft < 4; ++ft)
                af[ft] = Xv[(wy * 64 + ft * 16 + r15) * 8 + sg];
#pragma unroll
            for (int fj = 0; fj < 4; ++fj)
                bw[fj] = Wv[(wx * 64 + fj * 16 + r15) * 8 + sg];
#pragma unroll
            for (int ft = 0; ft < 4; ++ft)
#pragma unroll
                for (int fj = 0; fj < 4; ++fj)
                    acc[ft][fj] = __builtin_amdgcn_mfma_f32_16x16x32_bf16(
                        af[ft], bw[fj], acc[ft][fj], 0, 0, 0);
        }
    };

    const int nkt = K >> 6;   // 10 / 16 / 8 — always even

    STAGE(Xs0, Ws0);          // tile 0 in flight (8 loads)

    for (int kt2 = 0; kt2 < nkt; kt2 += 2) {
        // ---- tile kt2 (buf0); prefetch kt2+1 (buf1) ----
        STAGE(Xs1, Ws1);
        asm volatile("s_waitcnt vmcnt(8)" ::: "memory");
        __builtin_amdgcn_s_barrier();
        __builtin_amdgcn_sched_barrier(0);
        compute(Xs0, Ws0);
        __builtin_amdgcn_sched_barrier(0);
        __builtin_amdgcn_s_barrier();

        // ---- tile kt2+1 (buf1); prefetch kt2+2 (buf0) if any ----
        if (kt2 + 2 < nkt) {
            STAGE(Xs0, Ws0);
            asm volatile("s_waitcnt vmcnt(8)" ::: "memory");
        } else {
            asm volatile("s_waitcnt vmcnt(0)" ::: "memory");
        }
        __builtin_amdgcn_s_barrier();
        __builtin_amdgcn_sched_barrier(0);
        compute(Xs1, Ws1);
        __builtin_amdgcn_sched_barrier(0);
        __builtin_amdgcn_s_barrier();
    }
#undef STAGE

#pragma unroll
    for (int ft = 0; ft < 4; ++ft) {
#pragma unroll
        for (int r = 0; r < 4; ++r) {
            int t = t0 + wy * 64 + ft * 16 + q * 4 + r;
            if (t < TGT) {
                size_t rowoff = ((size_t)(b * TGT + t)) * M;
#pragma unroll
                for (int fj = 0; fj < 4; ++fj) {
                    int m = m0 + wx * 64 + fj * 16 + r15;
                    float v = acc[ft][fj][r];
                    if (bias) v += bias[m];
                    if (RELU_OUT) v = fmaxf(v, 0.f);
                    if (OUT_BF16)
                        ((__hip_bfloat16*)Y)[rowoff + m] = __float2bfloat16(v);
                    else
                        ((float*)Y)[rowoff + m] = v;
                }
            }
        }
    }
}

// ============================================================
extern "C" void kernel_launch(void* const* d_in, const int* in_sizes, int n_in,
                              void* d_out, int out_size, void* d_ws, size_t ws_size,
                              hipStream_t stream)
{
    const float* inputs   = (const float*)d_in[0];
    const float* cond     = (const float*)d_in[1];
    const float* input_w  = (const float*)d_in[2];
    const float* filter_w = (const float*)d_in[3];
    const float* gate_w   = (const float*)d_in[4];
    const float* res_w    = (const float*)d_in[5];
    const float* split_w  = (const float*)d_in[6];
    const float* gcf_w    = (const float*)d_in[7];
    const float* gcs_w    = (const float*)d_in[8];
    const float* f1_w     = (const float*)d_in[9];
    const float* f1_b     = (const float*)d_in[10];
    const float* f2_w     = (const float*)d_in[11];
    const float* f2_b     = (const float*)d_in[12];
    float* out = (float*)d_out;

    char* wsb = (char*)d_ws;
    const size_t RES_B   = (size_t)Bc * RCc * Lc * 4;        // 2 MB each
    const size_t OUTS_B  = (size_t)Bc * TGT * KTOT * 2;      // 15.7 MB
    const size_t FIN_B   = (size_t)Bc * TGT * SCc * 2;       // 25.2 MB
    const size_t H1_B    = (size_t)Bc * TGT * ECc * 2;       // 12.6 MB
    const size_t W1_B    = (size_t)SCc * KTOT * 2;
    const size_t W2_B    = (size_t)ECc * SCc * 2;
    const size_t W3_B    = (size_t)OCc * ECc * 2;
    const size_t WFG_B   = (size_t)NL * 64 * 64 * 2;         // 160 KB
    const size_t WR_B    = (size_t)NL * 32 * 64 * 2;         // 80 KB

    float* res0              = (float*)wsb;                   size_t off = RES_B;
    float* res1              = (float*)(wsb + off);           off += RES_B;
    __hip_bfloat16* outsT    = (__hip_bfloat16*)(wsb + off);  off += OUTS_B;
    __hip_bfloat16* finalT   = (__hip_bfloat16*)(wsb + off);  off += FIN_B;
    __hip_bfloat16* h1T      = (__hip_bfloat16*)(wsb + off);  off += H1_B;
    __hip_bfloat16* Wp1      = (__hip_bfloat16*)(wsb + off);  off += W1_B;
    __hip_bfloat16* Wp2      = (__hip_bfloat16*)(wsb + off);  off += W2_B;
    __hip_bfloat16* Wp3      = (__hip_bfloat16*)(wsb + off);  off += W3_B;
    __hip_bfloat16* wfgp     = (__hip_bfloat16*)(wsb + off);  off += WFG_B;
    __hip_bfloat16* wrp      = (__hip_bfloat16*)(wsb + off);  off += WR_B;

    // weight packs (independent of activations)
    pack_w1<<<(SCc * KTOT + 255) / 256, 256, 0, stream>>>(split_w, Wp1);
    pack_plain<<<(ECc * SCc + 255) / 256, 256, 0, stream>>>(f1_w, Wp2, ECc * SCc);
    pack_plain<<<(OCc * ECc + 255) / 256, 256, 0, stream>>>(f2_w, Wp3, OCc * ECc);
    pack_wfgr<<<(NL * 64 * 64 + 255) / 256, 256, 0, stream>>>(
        filter_w, gate_w, res_w, wfgp, wrp);

    input_conv<<<dim3(Lc / 64, Bc), 256, 0, stream>>>(inputs, input_w, res0);

    float* rin = res0;
    float* rout = res1;
    for (int i = 0; i < NL; ++i) {
        int d = 1 << (i % 10);
        const __hip_bfloat16* wfg = wfgp + (size_t)i * 64 * 64;
        const __hip_bfloat16* wr  = wrp  + (size_t)i * 32 * 64;
        if (i + 1 < NL)
            layer_mfma<false><<<dim3(Lc / 64, Bc), 256, 0, stream>>>(
                rin, rout, outsT, wfg, wr, cond, gcf_w + i * 5, gcs_w + i * 5, d, i);
        else
            layer_mfma<true><<<dim3(Lc / 64, Bc), 256, 0, stream>>>(
                rin, rout, outsT, wfg, wr, cond, gcf_w + i * 5, gcs_w + i * 5, d, i);
        float* tmp = rin; rin = rout; rout = tmp;
    }

    // G1: finalT = relu( outsT(12292x640) @ Wp1^T )   -> bf16 [t][1024]
    gemm_mfma<true, true><<<dim3(SCc / 128, Bc * TTILES), 256, 0, stream>>>(
        outsT, Wp1, nullptr, finalT, SCc, KTOT);

    // G2: h1T = relu( finalT @ Wp2^T + f1_b )         -> bf16 [t][512]
    gemm_mfma<true, true><<<dim3(ECc / 128, Bc * TTILES), 256, 0, stream>>>(
        finalT, Wp2, f1_b, h1T, ECc, SCc);

    // G3: out = h1T @ Wp3^T + f2_b                    -> fp32 [t][256] (final layout)
    gemm_mfma<false, false><<<dim3(OCc / 128, Bc * TTILES), 256, 0, stream>>>(
        h1T, Wp3, f2_b, out, OCc, ECc);
}

// Round 9
// 260.909 us; speedup vs baseline: 1.7529x; 1.1435x over previous
//
#include <hip/hip_runtime.h>
#include <hip/hip_bf16.h>
#include <cstddef>

// ---- problem constants ----
#define Bc   2
#define Lc   8192
#define TGT  6146          // L - RF, RF = 2046
#define NL   20            // layers
#define RCc  32
#define DCc  32
#define SCc  1024
#define ECc  512
#define OCc  256
#define KTOT (NL * DCc)    // 640
#define TTILES 49          // ceil(TGT/128)

typedef __attribute__((ext_vector_type(4))) float f32x4;
typedef __attribute__((ext_vector_type(8))) short bf16x8;
typedef __attribute__((ext_vector_type(4))) int i32x4;
typedef __attribute__((ext_vector_type(2))) int i32x2;

typedef __attribute__((address_space(1))) void* as1v;
typedef __attribute__((address_space(3))) void* as3v;

__device__ inline bf16x8 cvt8(const float4* p) {
    float4 a = p[0], b = p[1];
    union { bf16x8 v; __hip_bfloat16 h[8]; } u;
    u.h[0] = __float2bfloat16(a.x); u.h[1] = __float2bfloat16(a.y);
    u.h[2] = __float2bfloat16(a.z); u.h[3] = __float2bfloat16(a.w);
    u.h[4] = __float2bfloat16(b.x); u.h[5] = __float2bfloat16(b.y);
    u.h[6] = __float2bfloat16(b.z); u.h[7] = __float2bfloat16(b.w);
    return u.v;
}

// ============================================================
// K0: input 1x1 conv  (B,256,L) x (32,256) -> res (B,32,L)
// ============================================================
__global__ __launch_bounds__(256) void input_conv(
    const float* __restrict__ x,   // [B][256][L]
    const float* __restrict__ w,   // [32][256]
    float* __restrict__ res_out)   // [B][32][L]
{
    __shared__ float ws[32][256];
    __shared__ float xs[64][64];
    int tid = threadIdx.x;
    int b   = blockIdx.y;
    int t0  = blockIdx.x * 64;

    for (int idx = tid; idx < 32 * 256; idx += 256)
        ws[idx >> 8][idx & 255] = w[idx];

    int tl = tid & 63, qq = tid >> 6, oc0 = qq * 8;
    float acc[8] = {};

    for (int icc = 0; icc < 4; ++icc) {
        __syncthreads();
        for (int idx = tid; idx < 64 * 64; idx += 256) {
            int icl = idx >> 6, tll = idx & 63;
            xs[icl][tll] = x[((size_t)b * 256 + icc * 64 + icl) * Lc + t0 + tll];
        }
        __syncthreads();
        for (int icl = 0; icl < 64; icl += 4) {
            float x0 = xs[icl][tl], x1 = xs[icl + 1][tl];
            float x2 = xs[icl + 2][tl], x3 = xs[icl + 3][tl];
#pragma unroll
            for (int j = 0; j < 8; ++j) {
                const float4 w4 = *(const float4*)&ws[oc0 + j][icc * 64 + icl];
                acc[j] += w4.x * x0 + w4.y * x1 + w4.z * x2 + w4.w * x3;
            }
        }
    }
#pragma unroll
    for (int j = 0; j < 8; ++j)
        res_out[((size_t)b * 32 + oc0 + j) * Lc + t0 + tl] = acc[j];
}

// ============================================================
// ONE pack kernel for everything (fp32 -> bf16 + swizzles)
// ============================================================
__global__ void pack_all(const float* __restrict__ split_w,
                         const float* __restrict__ f1_w,
                         const float* __restrict__ f2_w,
                         const float* __restrict__ filt,
                         const float* __restrict__ gate,
                         const float* __restrict__ resw,
                         __hip_bfloat16* __restrict__ Wp1,
                         __hip_bfloat16* __restrict__ Wp2,
                         __hip_bfloat16* __restrict__ Wp3,
                         __hip_bfloat16* __restrict__ wfgp,
                         __hip_bfloat16* __restrict__ wrp)
{
    int idx = blockIdx.x * 256 + threadIdx.x;
    const int N1 = SCc * KTOT, N2 = ECc * SCc, N3 = OCc * ECc, N4 = NL * 64 * 64;
    if (idx < N1) {
        int m = idx / KTOT, k = idx % KTOT;
        int i = k >> 5, c = k & 31;
        Wp1[idx] = __float2bfloat16(split_w[((size_t)i * SCc + m) * DCc + c]);
        return;
    }
    idx -= N1;
    if (idx < N2) { Wp2[idx] = __float2bfloat16(f1_w[idx]); return; }
    idx -= N2;
    if (idx < N3) { Wp3[idx] = __float2bfloat16(f2_w[idx]); return; }
    idx -= N3;
    if (idx < N4) {
        int li = idx / 4096, r = idx % 4096;
        int m = r >> 6, k = r & 63;
        int tap = k >> 5, ic = k & 31;
        float v = (m < 32) ? filt[(size_t)li * 2048 + (m * 32 + ic) * 2 + tap]
                           : gate[(size_t)li * 2048 + ((m - 32) * 32 + ic) * 2 + tap];
        int slot = (k >> 3) ^ (m & 7);
        wfgp[((size_t)li * 64 + m) * 64 + slot * 8 + (k & 7)] = __float2bfloat16(v);
        if (r < 2048) {
            int m2 = r >> 6;   // 0..31
            float v2 = (k < 32) ? resw[(size_t)li * 1024 + m2 * 32 + k] : 0.f;
            wrp[((size_t)li * 32 + m2) * 64 + slot * 8 + (k & 7)] = __float2bfloat16(v2);
        }
    }
}

// ============================================================
// grouped layers: NLAY layers (dil = D0<<i) in one kernel.
// Tile = 64 output cols + H = W-64 halo (recompute). Residual
// fp32 in LDS (rows padded to 36 floats); o bf16 [W][40] rows.
// Math bit-identical to layer_mfma (same MFMA order/rounding).
// ============================================================
template <int NLAY, int D0, int W>
__global__ __launch_bounds__(256) void layer_group(
    const float* __restrict__ res_in,   // [B][32][L]
    float* __restrict__ res_out,        // [B][32][L]
    __hip_bfloat16* __restrict__ outsT, // [B*TGT][640]
    const __hip_bfloat16* __restrict__ wfgp,  // all-layer base (pre-swizzled)
    const __hip_bfloat16* __restrict__ wrp,
    const float* __restrict__ cond,
    const float* __restrict__ gcf_w,    // [NL][5]
    const float* __restrict__ gcs_w,
    int l0)
{
    constexpr int H  = W - 64;
    constexpr int NT = W / 16;
    __shared__ __align__(16) float resL[W * 36];
    __shared__ __align__(16) unsigned short OsL[W * 40];
    __shared__ __align__(16) i32x4 Wf[64 * 8];
    __shared__ __align__(16) i32x4 Wrs[32 * 8];

    int tid  = threadIdx.x;
    int b    = blockIdx.y;
    int t0   = blockIdx.x * 64;
    int lane = tid & 63, wid = tid >> 6;
    int r15  = lane & 15, q = lane >> 4;

    // stage residual tile (coalesced global fp32; tg<0 -> causal zero pad)
    const float* rb = res_in + (size_t)b * 32 * Lc;
    for (int idx = tid; idx < W * 32; idx += 256) {
        int ch = idx / W, tl = idx % W;
        int tg = t0 - H + tl;
        resL[tl * 36 + ch] = (tg >= 0) ? rb[(size_t)ch * Lc + tg] : 0.f;
    }

    for (int i = 0; i < NLAY; ++i) {
        int li = l0 + i;
        int d  = D0 << i;
        const __hip_bfloat16* wfg = wfgp + (size_t)li * 4096;
        const __hip_bfloat16* wrl = wrp  + (size_t)li * 2048;
#pragma unroll
        for (int c = 0; c < 2; ++c)
            __builtin_amdgcn_global_load_lds(
                (as1v)(void*)((const i32x4*)wfg + (wid * 2 + c) * 64 + lane),
                (as3v)(void*)&Wf[(wid * 2 + c) * 64], 16, 0, 0);
        __builtin_amdgcn_global_load_lds(
            (as1v)(void*)((const i32x4*)wrl + wid * 64 + lane),
            (as3v)(void*)&Wrs[wid * 64], 16, 0, 0);

        float gf = 0.f, gg = 0.f;
#pragma unroll
        for (int c = 0; c < 5; ++c) {
            gf += gcf_w[li * 5 + c] * cond[b * 5 + c];
            gg += gcs_w[li * 5 + c] * cond[b * 5 + c];
        }
        __syncthreads();   // weights staged; prev phase-3 done (drains vm+lgkm)

        // ---- phase 1: gated conv MFMA over all tiles ----
        const bf16x8* Wv = (const bf16x8*)Wf;
        for (int tt = wid; tt < NT; tt += 4) {
            int ct0 = tt * 16;
            int srow0 = ct0 + r15 - d; if (srow0 < 0) srow0 = 0;   // halo clamp (garbage cols only)
            int srow1 = ct0 + r15;
            bf16x8 a0 = cvt8((const float4*)&resL[srow0 * 36 + q * 8]);
            bf16x8 a1 = cvt8((const float4*)&resL[srow1 * 36 + q * 8]);
            int sg0 = q ^ (r15 & 7), sg1 = (4 + q) ^ (r15 & 7);
            f32x4 acc[4] = {};
#pragma unroll
            for (int fj = 0; fj < 4; ++fj)
                acc[fj] = __builtin_amdgcn_mfma_f32_16x16x32_bf16(
                    a0, Wv[(fj * 16 + r15) * 8 + sg0], acc[fj], 0, 0, 0);
#pragma unroll
            for (int fj = 0; fj < 4; ++fj)
                acc[fj] = __builtin_amdgcn_mfma_f32_16x16x32_bf16(
                    a1, Wv[(fj * 16 + r15) * 8 + sg1], acc[fj], 0, 0, 0);
#pragma unroll
            for (int fj = 0; fj < 2; ++fj) {
#pragma unroll
                for (int r = 0; r < 4; ++r) {
                    float F = acc[fj][r] + gf;
                    float G = acc[fj + 2][r] + gg;
                    float th  = 1.f - 2.f / (__expf(2.f * F) + 1.f);
                    float sgm = 1.f / (1.f + __expf(-G));
                    float o   = th * sgm;
                    int col = ct0 + q * 4 + r;
                    int ch  = fj * 16 + r15;
                    __hip_bfloat16 ob = __float2bfloat16(o);
                    OsL[col * 40 + ch] = *(unsigned short*)&ob;
                    int tg = t0 + col - H;
                    if (col >= H && tg >= Lc - TGT)
                        outsT[((size_t)(b * TGT + tg - (Lc - TGT))) * KTOT + li * 32 + ch] = ob;
                }
            }
        }
        __syncthreads();   // Os ready; all resL reads done

        // ---- phase 3: residual conv MFMA + RMW resL ----
        const bf16x8* Rv = (const bf16x8*)Wrs;
        const bf16x8* Ov = (const bf16x8*)OsL;
        for (int tt = wid; tt < NT; tt += 4) {
            int ct0 = tt * 16;
            bf16x8 ao = Ov[(ct0 + r15) * 5 + q];
            int sg = q ^ (r15 & 7);
            f32x4 racc[2] = {};
#pragma unroll
            for (int fj = 0; fj < 2; ++fj)
                racc[fj] = __builtin_amdgcn_mfma_f32_16x16x32_bf16(
                    ao, Rv[(fj * 16 + r15) * 8 + sg], racc[fj], 0, 0, 0);
#pragma unroll
            for (int fj = 0; fj < 2; ++fj)
#pragma unroll
                for (int r = 0; r < 4; ++r) {
                    int col = ct0 + q * 4 + r;
                    int ch  = fj * 16 + r15;
                    if (t0 + col - H >= 0)               // keep causal-pad rows zero
                        resL[col * 36 + ch] += racc[fj][r];
                }
        }
        __syncthreads();   // res updated before next layer / final write
    }

    // ---- final: write own 64 output cols fp32 coalesced ----
    {
        int ch = tid >> 3, t8 = (tid & 7) * 8;
        float v[8];
#pragma unroll
        for (int j = 0; j < 8; ++j) v[j] = resL[(H + t8 + j) * 36 + ch];
        float* ro = res_out + ((size_t)(b * 32) + ch) * Lc + t0 + t8;
        *(float4*)ro       = make_float4(v[0], v[1], v[2], v[3]);
        *(float4*)(ro + 4) = make_float4(v[4], v[5], v[6], v[7]);
    }
}

// ============================================================
// single-layer MFMA kernel (for d=256/512)
// ============================================================
template <bool SKIPRES>
__global__ __launch_bounds__(256) void layer_mfma(
    const float* __restrict__ res_in,
    float* __restrict__ res_out,
    __hip_bfloat16* __restrict__ outsT,
    const __hip_bfloat16* __restrict__ wfg,  // [64][64] (pre-swizzled)
    const __hip_bfloat16* __restrict__ wr,   // [32][64] (pre-swizzled)
    const float* __restrict__ cond,
    const float* __restrict__ gcf,
    const float* __restrict__ gcs,
    int dil, int li)
{
    __shared__ __align__(16) i32x4 Xs[64 * 8];
    __shared__ __align__(16) i32x4 Wf[64 * 8];
    __shared__ __align__(16) i32x4 Wrs[32 * 8];
    __shared__ __align__(16) unsigned short Os[64 * 64];
    __shared__ float Rxf[32][65];

    int tid  = threadIdx.x;
    int b    = blockIdx.y;
    int t0   = blockIdx.x * 64;
    int lane = tid & 63, wid = tid >> 6;
    int r15  = lane & 15, q = lane >> 4;
    int wt0  = wid * 16;

#pragma unroll
    for (int c = 0; c < 2; ++c)
        __builtin_amdgcn_global_load_lds(
            (as1v)(void*)((const i32x4*)wfg + (wid * 2 + c) * 64 + lane),
            (as3v)(void*)&Wf[(wid * 2 + c) * 64], 16, 0, 0);
    if (!SKIPRES)
        __builtin_amdgcn_global_load_lds(
            (as1v)(void*)((const i32x4*)wr + wid * 64 + lane),
            (as3v)(void*)&Wrs[wid * 64], 16, 0, 0);

    {
        int tloc = tid >> 2;
        int tg   = t0 + tloc;
        const float* rb = res_in + (size_t)b * 32 * Lc;
#pragma unroll
        for (int gi = 0; gi < 2; ++gi) {
            int g = (tid & 3) * 2 + gi;
            union { i32x4 v; __hip_bfloat16 h[8]; } u;
#pragma unroll
            for (int j = 0; j < 8; ++j) {
                int k = g * 8 + j;
                float v;
                if (k < 32) v = (tg >= dil) ? rb[(size_t)k * Lc + tg - dil] : 0.f;
                else        v = rb[(size_t)(k - 32) * Lc + tg];
                u.h[j] = __float2bfloat16(v);
            }
            Xs[tloc * 8 + (g ^ (tloc & 7))] = u.v;
        }
    }

    float gf = gcf[0] * cond[b * 5 + 0] + gcf[1] * cond[b * 5 + 1] +
               gcf[2] * cond[b * 5 + 2] + gcf[3] * cond[b * 5 + 3] +
               gcf[4] * cond[b * 5 + 4];
    float gg = gcs[0] * cond[b * 5 + 0] + gcs[1] * cond[b * 5 + 1] +
               gcs[2] * cond[b * 5 + 2] + gcs[3] * cond[b * 5 + 3] +
               gcs[4] * cond[b * 5 + 4];

    __syncthreads();

    const bf16x8* Xv = (const bf16x8*)Xs;
    const bf16x8* Wv = (const bf16x8*)Wf;
    f32x4 acc[4] = {};
#pragma unroll
    for (int kk = 0; kk < 2; ++kk) {
        int sg = (kk * 4 + q) ^ (r15 & 7);
        bf16x8 af = Xv[(wt0 + r15) * 8 + sg];
#pragma unroll
        for (int fj = 0; fj < 4; ++fj)
            acc[fj] = __builtin_amdgcn_mfma_f32_16x16x32_bf16(
                af, Wv[(fj * 16 + r15) * 8 + sg], acc[fj], 0, 0, 0);
    }

#pragma unroll
    for (int fj = 0; fj < 2; ++fj) {
#pragma unroll
        for (int r = 0; r < 4; ++r) {
            float F = acc[fj][r] + gf;
            float G = acc[fj + 2][r] + gg;
            float th = 1.f - 2.f / (__expf(2.f * F) + 1.f);
            float sg = 1.f / (1.f + __expf(-G));
            float o  = th * sg;
            int tl2 = wt0 + q * 4 + r;
            int ic  = fj * 16 + r15;
            __hip_bfloat16 ob = __float2bfloat16(o);
            if (!SKIPRES) {
                int gsl = (ic >> 3) ^ (tl2 & 7);
                Os[tl2 * 64 + gsl * 8 + (ic & 7)] = *(unsigned short*)&ob;
            }
            int tgo = t0 + tl2;
            if (tgo >= Lc - TGT)
                outsT[((size_t)(b * TGT + tgo - (Lc - TGT))) * KTOT + li * 32 + ic] = ob;
        }
    }

    if (!SKIPRES) {
        __syncthreads();
        const bf16x8* Ov  = (const bf16x8*)Os;
        const bf16x8* Rv  = (const bf16x8*)Wrs;
        int sg = q ^ (r15 & 7);
        bf16x8 ao = Ov[(wt0 + r15) * 8 + sg];
        f32x4 racc[2] = {};
#pragma unroll
        for (int fj = 0; fj < 2; ++fj)
            racc[fj] = __builtin_amdgcn_mfma_f32_16x16x32_bf16(
                ao, Rv[(fj * 16 + r15) * 8 + sg], racc[fj], 0, 0, 0);

#pragma unroll
        for (int fj = 0; fj < 2; ++fj)
#pragma unroll
            for (int r = 0; r < 4; ++r)
                Rxf[fj * 16 + r15][wt0 + q * 4 + r] = racc[fj][r];
        __syncthreads();

        int row = tid >> 3, ch = tid & 7;
        size_t ga = ((size_t)(b * 32) + row) * Lc + t0 + ch * 8;
        const float4* ri = (const float4*)(res_in + ga);
        float4* ro = (float4*)(res_out + ga);
        const float* rx = &Rxf[row][ch * 8];
        float4 a0 = ri[0], a1 = ri[1];
        a0.x += rx[0]; a0.y += rx[1]; a0.z += rx[2]; a0.w += rx[3];
        a1.x += rx[4]; a1.y += rx[5]; a1.z += rx[6]; a1.w += rx[7];
        ro[0] = a0; ro[1] = a1;
    }
}

// ============================================================
// bf16 MFMA GEMM, 2-phase double-buffered, counted vmcnt (T3+T4)
// ============================================================
template <bool RELU_OUT, bool OUT_BF16>
__global__ __launch_bounds__(256) void gemm_mfma(
    const __hip_bfloat16* __restrict__ X,
    const __hip_bfloat16* __restrict__ W,
    const float* __restrict__ bias,
    void* __restrict__ Y,
    int M, int K)
{
    __shared__ i32x4 Xs0[128 * 8];
    __shared__ i32x4 Ws0[128 * 8];
    __shared__ i32x4 Xs1[128 * 8];
    __shared__ i32x4 Ws1[128 * 8];

    int tid = threadIdx.x;
    int m0  = blockIdx.x * 128;
    int by  = blockIdx.y;
    int b   = by / TTILES;
    int t0  = (by % TTILES) * 128;

    int lane = tid & 63, wid = tid >> 6;
    int wy = wid >> 1, wx = wid & 1;
    int r15 = lane & 15, q = lane >> 4;

    int subrow = lane >> 3;
    int g      = (lane & 7) ^ subrow;
    const __hip_bfloat16* xp[4];
    const __hip_bfloat16* wp[4];
#pragma unroll
    for (int i = 0; i < 4; ++i) {
        int r = wid * 32 + i * 8 + subrow;
        int xrow = t0 + r; if (xrow > TGT - 1) xrow = TGT - 1;
        xp[i] = X + ((size_t)(b * TGT + xrow)) * K + g * 8;
        wp[i] = W + ((size_t)(m0 + r)) * K + g * 8;
    }

    f32x4 acc[4][4] = {};

#define STAGE(XB, WB)                                                          \
    {                                                                          \
        _Pragma("unroll")                                                      \
        for (int i = 0; i < 4; ++i) {                                          \
            __builtin_amdgcn_global_load_lds((as1v)(void*)xp[i],               \
                (as3v)(void*)&XB[(wid * 4 + i) * 64], 16, 0, 0);               \
            __builtin_amdgcn_global_load_lds((as1v)(void*)wp[i],               \
                (as3v)(void*)&WB[(wid * 4 + i) * 64], 16, 0, 0);               \
            xp[i] += 64; wp[i] += 64;                                          \
        }                                                                      \
    }

    auto compute = [&](const i32x4* Xb, const i32x4* Wb) {
        const bf16x8* Xv = (const bf16x8*)Xb;
        const bf16x8* Wv = (const bf16x8*)Wb;
#pragma unroll
        for (int kk = 0; kk < 2; ++kk) {
            int sg = (kk * 4 + q) ^ (r15 & 7);
            bf16x8 af[4], bw[4];
#pragma unroll
            for (int ft = 0; ft < 4; ++ft)
                af[ft] = Xv[(wy * 64 + ft * 16 + r15) * 8 + sg];
#pragma unroll
            for (int fj = 0; fj < 4; ++fj)
                bw[fj] = Wv[(wx * 64 + fj * 16 + r15) * 8 + sg];
#pragma unroll
            for (int ft = 0; ft < 4; ++ft)
#pragma unroll
                for (int fj = 0; fj < 4; ++fj)
                    acc[ft][fj] = __builtin_amdgcn_mfma_f32_16x16x32_bf16(
                        af[ft], bw[fj], acc[ft][fj], 0, 0, 0);
        }
    };

    const int nkt = K >> 6;   // 10 / 16 / 8 — always even

    STAGE(Xs0, Ws0);

    for (int kt2 = 0; kt2 < nkt; kt2 += 2) {
        STAGE(Xs1, Ws1);
        asm volatile("s_waitcnt vmcnt(8)" ::: "memory");
        __builtin_amdgcn_s_barrier();
        __builtin_amdgcn_sched_barrier(0);
        compute(Xs0, Ws0);
        __builtin_amdgcn_sched_barrier(0);
        __builtin_amdgcn_s_barrier();

        if (kt2 + 2 < nkt) {
            STAGE(Xs0, Ws0);
            asm volatile("s_waitcnt vmcnt(8)" ::: "memory");
        } else {
            asm volatile("s_waitcnt vmcnt(0)" ::: "memory");
        }
        __builtin_amdgcn_s_barrier();
        __builtin_amdgcn_sched_barrier(0);
        compute(Xs1, Ws1);
        __builtin_amdgcn_sched_barrier(0);
        __builtin_amdgcn_s_barrier();
    }
#undef STAGE

#pragma unroll
    for (int ft = 0; ft < 4; ++ft) {
#pragma unroll
        for (int r = 0; r < 4; ++r) {
            int t = t0 + wy * 64 + ft * 16 + q * 4 + r;
            if (t < TGT) {
                size_t rowoff = ((size_t)(b * TGT + t)) * M;
#pragma unroll
                for (int fj = 0; fj < 4; ++fj) {
                    int m = m0 + wx * 64 + fj * 16 + r15;
                    float v = acc[ft][fj][r];
                    if (bias) v += bias[m];
                    if (RELU_OUT) v = fmaxf(v, 0.f);
                    if (OUT_BF16)
                        ((__hip_bfloat16*)Y)[rowoff + m] = __float2bfloat16(v);
                    else
                        ((float*)Y)[rowoff + m] = v;
                }
            }
        }
    }
}

// ============================================================
extern "C" void kernel_launch(void* const* d_in, const int* in_sizes, int n_in,
                              void* d_out, int out_size, void* d_ws, size_t ws_size,
                              hipStream_t stream)
{
    const float* inputs   = (const float*)d_in[0];
    const float* cond     = (const float*)d_in[1];
    const float* input_w  = (const float*)d_in[2];
    const float* filter_w = (const float*)d_in[3];
    const float* gate_w   = (const float*)d_in[4];
    const float* res_w    = (const float*)d_in[5];
    const float* split_w  = (const float*)d_in[6];
    const float* gcf_w    = (const float*)d_in[7];
    const float* gcs_w    = (const float*)d_in[8];
    const float* f1_w     = (const float*)d_in[9];
    const float* f1_b     = (const float*)d_in[10];
    const float* f2_w     = (const float*)d_in[11];
    const float* f2_b     = (const float*)d_in[12];
    float* out = (float*)d_out;

    char* wsb = (char*)d_ws;
    const size_t RES_B   = (size_t)Bc * RCc * Lc * 4;
    const size_t OUTS_B  = (size_t)Bc * TGT * KTOT * 2;
    const size_t FIN_B   = (size_t)Bc * TGT * SCc * 2;
    const size_t H1_B    = (size_t)Bc * TGT * ECc * 2;
    const size_t W1_B    = (size_t)SCc * KTOT * 2;
    const size_t W2_B    = (size_t)ECc * SCc * 2;
    const size_t W3_B    = (size_t)OCc * ECc * 2;
    const size_t WFG_B   = (size_t)NL * 64 * 64 * 2;
    const size_t WR_B    = (size_t)NL * 32 * 64 * 2;

    float* res0              = (float*)wsb;                   size_t off = RES_B;
    float* res1              = (float*)(wsb + off);           off += RES_B;
    __hip_bfloat16* outsT    = (__hip_bfloat16*)(wsb + off);  off += OUTS_B;
    __hip_bfloat16* finalT   = (__hip_bfloat16*)(wsb + off);  off += FIN_B;
    __hip_bfloat16* h1T      = (__hip_bfloat16*)(wsb + off);  off += H1_B;
    __hip_bfloat16* Wp1      = (__hip_bfloat16*)(wsb + off);  off += W1_B;
    __hip_bfloat16* Wp2      = (__hip_bfloat16*)(wsb + off);  off += W2_B;
    __hip_bfloat16* Wp3      = (__hip_bfloat16*)(wsb + off);  off += W3_B;
    __hip_bfloat16* wfgp     = (__hip_bfloat16*)(wsb + off);  off += WFG_B;
    __hip_bfloat16* wrp      = (__hip_bfloat16*)(wsb + off);  off += WR_B;

    {
        const int NTOT = SCc * KTOT + ECc * SCc + OCc * ECc + NL * 64 * 64;
        pack_all<<<(NTOT + 255) / 256, 256, 0, stream>>>(
            split_w, f1_w, f2_w, filter_w, gate_w, res_w,
            Wp1, Wp2, Wp3, wfgp, wrp);
    }

    input_conv<<<dim3(Lc / 64, Bc), 256, 0, stream>>>(inputs, input_w, res0);

    float* rin = res0;
    float* rout = res1;
    const dim3 lgrid(Lc / 64, Bc);

    for (int half = 0; half < 2; ++half) {
        int l0 = half * 10;
        // layers l0..l0+4 (d=1..16)
        layer_group<5, 1, 96><<<lgrid, 256, 0, stream>>>(
            rin, rout, outsT, wfgp, wrp, cond, gcf_w, gcs_w, l0);
        { float* t = rin; rin = rout; rout = t; }
        // layers l0+5..l0+7 (d=32,64,128)
        layer_group<3, 32, 288><<<lgrid, 256, 0, stream>>>(
            rin, rout, outsT, wfgp, wrp, cond, gcf_w, gcs_w, l0 + 5);
        { float* t = rin; rin = rout; rout = t; }
        // layer l0+8 (d=256)
        {
            int li = l0 + 8;
            layer_mfma<false><<<lgrid, 256, 0, stream>>>(
                rin, rout, outsT, wfgp + (size_t)li * 4096, wrp + (size_t)li * 2048,
                cond, gcf_w + li * 5, gcs_w + li * 5, 256, li);
            float* t = rin; rin = rout; rout = t;
        }
        // layer l0+9 (d=512)
        {
            int li = l0 + 9;
            if (li == NL - 1)
                layer_mfma<true><<<lgrid, 256, 0, stream>>>(
                    rin, rout, outsT, wfgp + (size_t)li * 4096, wrp + (size_t)li * 2048,
                    cond, gcf_w + li * 5, gcs_w + li * 5, 512, li);
            else
                layer_mfma<false><<<lgrid, 256, 0, stream>>>(
                    rin, rout, outsT, wfgp + (size_t)li * 4096, wrp + (size_t)li * 2048,
                    cond, gcf_w + li * 5, gcs_w + li * 5, 512, li);
            float* t = rin; rin = rout; rout = t;
        }
    }

    // G1: finalT = relu( outsT(12292x640) @ Wp1^T )   -> bf16 [t][1024]
    gemm_mfma<true, true><<<dim3(SCc / 128, Bc * TTILES), 256, 0, stream>>>(
        outsT, Wp1, nullptr, finalT, SCc, KTOT);

    // G2: h1T = relu( finalT @ Wp2^T + f1_b )         -> bf16 [t][512]
    gemm_mfma<true, true><<<dim3(ECc / 128, Bc * TTILES), 256, 0, stream>>>(
        finalT, Wp2, f1_b, h1T, ECc, SCc);

    // G3: out = h1T @ Wp3^T + f2_b                    -> fp32 [t][256] (final layout)
    gemm_mfma<false, false><<<dim3(OCc / 128, Bc * TTILES), 256, 0, stream>>>(
        h1T, Wp3, f2_b, out, OCc, ECc);
}

// Round 10
// 226.739 us; speedup vs baseline: 2.0171x; 1.1507x over previous
//
#include <hip/hip_runtime.h>
#include <hip/hip_bf16.h>
#include <cstddef>

// ---- problem constants ----
#define Bc   2
#define Lc   8192
#define TGT  6146          // L - RF, RF = 2046
#define NL   20            // layers
#define RCc  32
#define DCc  32
#define SCc  1024
#define ECc  512
#define OCc  256
#define KTOT (NL * DCc)    // 640
#define TTILES 49          // ceil(TGT/128)

typedef __attribute__((ext_vector_type(4))) float f32x4;
typedef __attribute__((ext_vector_type(8))) short bf16x8;
typedef __attribute__((ext_vector_type(4))) int i32x4;
typedef __attribute__((ext_vector_type(2))) int i32x2;

typedef __attribute__((address_space(1))) void* as1v;
typedef __attribute__((address_space(3))) void* as3v;

__device__ inline bf16x8 cvt8(const float4* p) {
    float4 a = p[0], b = p[1];
    union { bf16x8 v; __hip_bfloat16 h[8]; } u;
    u.h[0] = __float2bfloat16(a.x); u.h[1] = __float2bfloat16(a.y);
    u.h[2] = __float2bfloat16(a.z); u.h[3] = __float2bfloat16(a.w);
    u.h[4] = __float2bfloat16(b.x); u.h[5] = __float2bfloat16(b.y);
    u.h[6] = __float2bfloat16(b.z); u.h[7] = __float2bfloat16(b.w);
    return u.v;
}

// ============================================================
// prep kernel: weight packs (blocks [0,npack)) + input 1x1 conv
// (blocks [npack, npack+256)) in ONE dispatch.
// ============================================================
__global__ __launch_bounds__(256) void prep_kernel(
    const float* __restrict__ x,        // [B][256][L]
    const float* __restrict__ iw,       // [32][256]
    float* __restrict__ res_out,        // [B][32][L]
    const float* __restrict__ split_w,
    const float* __restrict__ f1_w,
    const float* __restrict__ f2_w,
    const float* __restrict__ filt,
    const float* __restrict__ gate,
    const float* __restrict__ resw,
    __hip_bfloat16* __restrict__ Wp1,
    __hip_bfloat16* __restrict__ Wp2,
    __hip_bfloat16* __restrict__ Wp3,
    __hip_bfloat16* __restrict__ wfgp,
    __hip_bfloat16* __restrict__ wrp,
    int npack)
{
    __shared__ float ws[32][256];
    __shared__ float xs[64][64];
    int tid = threadIdx.x;

    if ((int)blockIdx.x < npack) {
        int idx = blockIdx.x * 256 + tid;
        const int N1 = SCc * KTOT, N2 = ECc * SCc, N3 = OCc * ECc, N4 = NL * 64 * 64;
        if (idx < N1) {
            int m = idx / KTOT, k = idx % KTOT;
            int i = k >> 5, c = k & 31;
            Wp1[idx] = __float2bfloat16(split_w[((size_t)i * SCc + m) * DCc + c]);
            return;
        }
        idx -= N1;
        if (idx < N2) { Wp2[idx] = __float2bfloat16(f1_w[idx]); return; }
        idx -= N2;
        if (idx < N3) { Wp3[idx] = __float2bfloat16(f2_w[idx]); return; }
        idx -= N3;
        if (idx < N4) {
            int li = idx / 4096, r = idx % 4096;
            int m = r >> 6, k = r & 63;
            int tap = k >> 5, ic = k & 31;
            float v = (m < 32) ? filt[(size_t)li * 2048 + (m * 32 + ic) * 2 + tap]
                               : gate[(size_t)li * 2048 + ((m - 32) * 32 + ic) * 2 + tap];
            int slot = (k >> 3) ^ (m & 7);
            wfgp[((size_t)li * 64 + m) * 64 + slot * 8 + (k & 7)] = __float2bfloat16(v);
            if (r < 2048) {
                int m2 = r >> 6;
                float v2 = (k < 32) ? resw[(size_t)li * 1024 + m2 * 32 + k] : 0.f;
                wrp[((size_t)li * 32 + m2) * 64 + slot * 8 + (k & 7)] = __float2bfloat16(v2);
            }
        }
        return;
    }

    // ---- input conv part ----
    int bid = blockIdx.x - npack;
    int b   = bid >> 7;
    int t0  = (bid & 127) * 64;

    for (int idx = tid; idx < 32 * 256; idx += 256)
        ws[idx >> 8][idx & 255] = iw[idx];

    int tl = tid & 63, qq = tid >> 6, oc0 = qq * 8;
    float acc[8] = {};

    for (int icc = 0; icc < 4; ++icc) {
        __syncthreads();
        for (int idx = tid; idx < 64 * 64; idx += 256) {
            int icl = idx >> 6, tll = idx & 63;
            xs[icl][tll] = x[((size_t)b * 256 + icc * 64 + icl) * Lc + t0 + tll];
        }
        __syncthreads();
        for (int icl = 0; icl < 64; icl += 4) {
            float x0 = xs[icl][tl], x1 = xs[icl + 1][tl];
            float x2 = xs[icl + 2][tl], x3 = xs[icl + 3][tl];
#pragma unroll
            for (int j = 0; j < 8; ++j) {
                const float4 w4 = *(const float4*)&ws[oc0 + j][icc * 64 + icl];
                acc[j] += w4.x * x0 + w4.y * x1 + w4.z * x2 + w4.w * x3;
            }
        }
    }
#pragma unroll
    for (int j = 0; j < 8; ++j)
        res_out[((size_t)b * 32 + oc0 + j) * Lc + t0 + tl] = acc[j];
}

// ============================================================
// grouped layers: NLAY layers (dil = D0<<i) in one kernel.
// 512 thr (8 waves). Tile = 64 out cols + H halo (recompute).
// Residual fp32 in LDS; o bf16 [W][40] rows. Math bit-identical
// to layer_mfma (same MFMA order/rounding).
// ============================================================
template <int NLAY, int D0, int W>
__global__ __launch_bounds__(512) void layer_group(
    const float* __restrict__ res_in,   // [B][32][L]
    float* __restrict__ res_out,        // [B][32][L]
    __hip_bfloat16* __restrict__ outsT, // [B*TGT][640]
    const __hip_bfloat16* __restrict__ wfgp,
    const __hip_bfloat16* __restrict__ wrp,
    const float* __restrict__ cond,
    const float* __restrict__ gcf_w,    // [NL][5]
    const float* __restrict__ gcs_w,
    int l0)
{
    constexpr int H  = W - 64;
    constexpr int NT = W / 16;
    __shared__ __align__(16) float resL[W * 36];
    __shared__ __align__(16) unsigned short OsL[W * 40];
    __shared__ __align__(16) i32x4 Wf[64 * 8];
    __shared__ __align__(16) i32x4 Wrs[32 * 8];

    int tid  = threadIdx.x;
    int b    = blockIdx.y;
    int t0   = blockIdx.x * 64;
    int lane = tid & 63, wid = tid >> 6;   // wid 0..7
    int r15  = lane & 15, q = lane >> 4;

    // stage residual tile (coalesced global fp32; tg<0 -> causal zero pad)
    const float* rb = res_in + (size_t)b * 32 * Lc;
    for (int idx = tid; idx < W * 32; idx += 512) {
        int ch = idx / W, tl = idx % W;
        int tg = t0 - H + tl;
        resL[tl * 36 + ch] = (tg >= 0) ? rb[(size_t)ch * Lc + tg] : 0.f;
    }

    for (int i = 0; i < NLAY; ++i) {
        int li = l0 + i;
        int d  = D0 << i;
        const __hip_bfloat16* wfg = wfgp + (size_t)li * 4096;
        const __hip_bfloat16* wrl = wrp  + (size_t)li * 2048;
        __builtin_amdgcn_global_load_lds(
            (as1v)(void*)((const i32x4*)wfg + wid * 64 + lane),
            (as3v)(void*)&Wf[wid * 64], 16, 0, 0);
        if (wid < 4)
            __builtin_amdgcn_global_load_lds(
                (as1v)(void*)((const i32x4*)wrl + wid * 64 + lane),
                (as3v)(void*)&Wrs[wid * 64], 16, 0, 0);

        float gf = 0.f, gg = 0.f;
#pragma unroll
        for (int c = 0; c < 5; ++c) {
            gf += gcf_w[li * 5 + c] * cond[b * 5 + c];
            gg += gcs_w[li * 5 + c] * cond[b * 5 + c];
        }
        __syncthreads();   // weights staged; prev phase-3 done

        // ---- phase 1: gated conv MFMA over all tiles ----
        const bf16x8* Wv = (const bf16x8*)Wf;
        for (int tt = wid; tt < NT; tt += 8) {
            int ct0 = tt * 16;
            int srow0 = ct0 + r15 - d; if (srow0 < 0) srow0 = 0;  // halo clamp (garbage cols only)
            int srow1 = ct0 + r15;
            bf16x8 a0 = cvt8((const float4*)&resL[srow0 * 36 + q * 8]);
            bf16x8 a1 = cvt8((const float4*)&resL[srow1 * 36 + q * 8]);
            int sg0 = q ^ (r15 & 7), sg1 = (4 + q) ^ (r15 & 7);
            f32x4 acc[4] = {};
#pragma unroll
            for (int fj = 0; fj < 4; ++fj)
                acc[fj] = __builtin_amdgcn_mfma_f32_16x16x32_bf16(
                    a0, Wv[(fj * 16 + r15) * 8 + sg0], acc[fj], 0, 0, 0);
#pragma unroll
            for (int fj = 0; fj < 4; ++fj)
                acc[fj] = __builtin_amdgcn_mfma_f32_16x16x32_bf16(
                    a1, Wv[(fj * 16 + r15) * 8 + sg1], acc[fj], 0, 0, 0);
#pragma unroll
            for (int fj = 0; fj < 2; ++fj) {
#pragma unroll
                for (int r = 0; r < 4; ++r) {
                    float F = acc[fj][r] + gf;
                    float G = acc[fj + 2][r] + gg;
                    float th  = 1.f - 2.f / (__expf(2.f * F) + 1.f);
                    float sgm = 1.f / (1.f + __expf(-G));
                    float o   = th * sgm;
                    int col = ct0 + q * 4 + r;
                    int ch  = fj * 16 + r15;
                    __hip_bfloat16 ob = __float2bfloat16(o);
                    OsL[col * 40 + ch] = *(unsigned short*)&ob;
                    int tg = t0 + col - H;
                    if (col >= H && tg >= Lc - TGT)
                        outsT[((size_t)(b * TGT + tg - (Lc - TGT))) * KTOT + li * 32 + ch] = ob;
                }
            }
        }
        __syncthreads();   // Os ready; all resL reads done

        // ---- phase 3: residual conv MFMA + RMW resL ----
        const bf16x8* Rv = (const bf16x8*)Wrs;
        const bf16x8* Ov = (const bf16x8*)OsL;
        for (int tt = wid; tt < NT; tt += 8) {
            int ct0 = tt * 16;
            bf16x8 ao = Ov[(ct0 + r15) * 5 + q];
            int sg = q ^ (r15 & 7);
            f32x4 racc[2] = {};
#pragma unroll
            for (int fj = 0; fj < 2; ++fj)
                racc[fj] = __builtin_amdgcn_mfma_f32_16x16x32_bf16(
                    ao, Rv[(fj * 16 + r15) * 8 + sg], racc[fj], 0, 0, 0);
#pragma unroll
            for (int fj = 0; fj < 2; ++fj)
#pragma unroll
                for (int r = 0; r < 4; ++r) {
                    int col = ct0 + q * 4 + r;
                    int ch  = fj * 16 + r15;
                    if (t0 + col - H >= 0)               // keep causal-pad rows zero
                        resL[col * 36 + ch] += racc[fj][r];
                }
        }
        __syncthreads();   // res updated before next layer / final write
    }

    // ---- final: write own 64 output cols fp32 coalesced ----
    {
        int ch = tid >> 4, t4 = (tid & 15) * 4;
        float v[4];
#pragma unroll
        for (int j = 0; j < 4; ++j) v[j] = resL[(H + t4 + j) * 36 + ch];
        float* ro = res_out + ((size_t)(b * 32) + ch) * Lc + t0 + t4;
        *(float4*)ro = make_float4(v[0], v[1], v[2], v[3]);
    }
}

// ============================================================
// single-layer MFMA kernel (for d=256/512)
// ============================================================
template <bool SKIPRES>
__global__ __launch_bounds__(256) void layer_mfma(
    const float* __restrict__ res_in,
    float* __restrict__ res_out,
    __hip_bfloat16* __restrict__ outsT,
    const __hip_bfloat16* __restrict__ wfg,  // [64][64] (pre-swizzled)
    const __hip_bfloat16* __restrict__ wr,   // [32][64] (pre-swizzled)
    const float* __restrict__ cond,
    const float* __restrict__ gcf,
    const float* __restrict__ gcs,
    int dil, int li)
{
    __shared__ __align__(16) i32x4 Xs[64 * 8];
    __shared__ __align__(16) i32x4 Wf[64 * 8];
    __shared__ __align__(16) i32x4 Wrs[32 * 8];
    __shared__ __align__(16) unsigned short Os[64 * 64];
    __shared__ float Rxf[32][65];

    int tid  = threadIdx.x;
    int b    = blockIdx.y;
    int t0   = blockIdx.x * 64;
    int lane = tid & 63, wid = tid >> 6;
    int r15  = lane & 15, q = lane >> 4;
    int wt0  = wid * 16;

#pragma unroll
    for (int c = 0; c < 2; ++c)
        __builtin_amdgcn_global_load_lds(
            (as1v)(void*)((const i32x4*)wfg + (wid * 2 + c) * 64 + lane),
            (as3v)(void*)&Wf[(wid * 2 + c) * 64], 16, 0, 0);
    if (!SKIPRES)
        __builtin_amdgcn_global_load_lds(
            (as1v)(void*)((const i32x4*)wr + wid * 64 + lane),
            (as3v)(void*)&Wrs[wid * 64], 16, 0, 0);

    {
        int tloc = tid >> 2;
        int tg   = t0 + tloc;
        const float* rb = res_in + (size_t)b * 32 * Lc;
#pragma unroll
        for (int gi = 0; gi < 2; ++gi) {
            int g = (tid & 3) * 2 + gi;
            union { i32x4 v; __hip_bfloat16 h[8]; } u;
#pragma unroll
            for (int j = 0; j < 8; ++j) {
                int k = g * 8 + j;
                float v;
                if (k < 32) v = (tg >= dil) ? rb[(size_t)k * Lc + tg - dil] : 0.f;
                else        v = rb[(size_t)(k - 32) * Lc + tg];
                u.h[j] = __float2bfloat16(v);
            }
            Xs[tloc * 8 + (g ^ (tloc & 7))] = u.v;
        }
    }

    float gf = gcf[0] * cond[b * 5 + 0] + gcf[1] * cond[b * 5 + 1] +
               gcf[2] * cond[b * 5 + 2] + gcf[3] * cond[b * 5 + 3] +
               gcf[4] * cond[b * 5 + 4];
    float gg = gcs[0] * cond[b * 5 + 0] + gcs[1] * cond[b * 5 + 1] +
               gcs[2] * cond[b * 5 + 2] + gcs[3] * cond[b * 5 + 3] +
               gcs[4] * cond[b * 5 + 4];

    __syncthreads();

    const bf16x8* Xv = (const bf16x8*)Xs;
    const bf16x8* Wv = (const bf16x8*)Wf;
    f32x4 acc[4] = {};
#pragma unroll
    for (int kk = 0; kk < 2; ++kk) {
        int sg = (kk * 4 + q) ^ (r15 & 7);
        bf16x8 af = Xv[(wt0 + r15) * 8 + sg];
#pragma unroll
        for (int fj = 0; fj < 4; ++fj)
            acc[fj] = __builtin_amdgcn_mfma_f32_16x16x32_bf16(
                af, Wv[(fj * 16 + r15) * 8 + sg], acc[fj], 0, 0, 0);
    }

#pragma unroll
    for (int fj = 0; fj < 2; ++fj) {
#pragma unroll
        for (int r = 0; r < 4; ++r) {
            float F = acc[fj][r] + gf;
            float G = acc[fj + 2][r] + gg;
            float th = 1.f - 2.f / (__expf(2.f * F) + 1.f);
            float sg = 1.f / (1.f + __expf(-G));
            float o  = th * sg;
            int tl2 = wt0 + q * 4 + r;
            int ic  = fj * 16 + r15;
            __hip_bfloat16 ob = __float2bfloat16(o);
            if (!SKIPRES) {
                int gsl = (ic >> 3) ^ (tl2 & 7);
                Os[tl2 * 64 + gsl * 8 + (ic & 7)] = *(unsigned short*)&ob;
            }
            int tgo = t0 + tl2;
            if (tgo >= Lc - TGT)
                outsT[((size_t)(b * TGT + tgo - (Lc - TGT))) * KTOT + li * 32 + ic] = ob;
        }
    }

    if (!SKIPRES) {
        __syncthreads();
        const bf16x8* Ov  = (const bf16x8*)Os;
        const bf16x8* Rv  = (const bf16x8*)Wrs;
        int sg = q ^ (r15 & 7);
        bf16x8 ao = Ov[(wt0 + r15) * 8 + sg];
        f32x4 racc[2] = {};
#pragma unroll
        for (int fj = 0; fj < 2; ++fj)
            racc[fj] = __builtin_amdgcn_mfma_f32_16x16x32_bf16(
                ao, Rv[(fj * 16 + r15) * 8 + sg], racc[fj], 0, 0, 0);

#pragma unroll
        for (int fj = 0; fj < 2; ++fj)
#pragma unroll
            for (int r = 0; r < 4; ++r)
                Rxf[fj * 16 + r15][wt0 + q * 4 + r] = racc[fj][r];
        __syncthreads();

        int row = tid >> 3, ch = tid & 7;
        size_t ga = ((size_t)(b * 32) + row) * Lc + t0 + ch * 8;
        const float4* ri = (const float4*)(res_in + ga);
        float4* ro = (float4*)(res_out + ga);
        const float* rx = &Rxf[row][ch * 8];
        float4 a0 = ri[0], a1 = ri[1];
        a0.x += rx[0]; a0.y += rx[1]; a0.z += rx[2]; a0.w += rx[3];
        a1.x += rx[4]; a1.y += rx[5]; a1.z += rx[6]; a1.w += rx[7];
        ro[0] = a0; ro[1] = a1;
    }
}

// ============================================================
// bf16 MFMA GEMM, 2-phase double-buffered, counted vmcnt (T3+T4).
// bf16 output path: epilogue exchanged through LDS -> 16B stores.
// ============================================================
template <bool RELU_OUT, bool OUT_BF16>
__global__ __launch_bounds__(256) void gemm_mfma(
    const __hip_bfloat16* __restrict__ X,
    const __hip_bfloat16* __restrict__ W,
    const float* __restrict__ bias,
    void* __restrict__ Y,
    int M, int K)
{
    __shared__ __align__(16) char smem[65536];
    i32x4* Xs0 = (i32x4*)smem;
    i32x4* Ws0 = (i32x4*)(smem + 16384);
    i32x4* Xs1 = (i32x4*)(smem + 32768);
    i32x4* Ws1 = (i32x4*)(smem + 49152);

    int tid = threadIdx.x;
    int m0  = blockIdx.x * 128;
    int by  = blockIdx.y;
    int b   = by / TTILES;
    int t0  = (by % TTILES) * 128;

    int lane = tid & 63, wid = tid >> 6;
    int wy = wid >> 1, wx = wid & 1;
    int r15 = lane & 15, q = lane >> 4;

    int subrow = lane >> 3;
    int g      = (lane & 7) ^ subrow;
    const __hip_bfloat16* xp[4];
    const __hip_bfloat16* wp[4];
#pragma unroll
    for (int i = 0; i < 4; ++i) {
        int r = wid * 32 + i * 8 + subrow;
        int xrow = t0 + r; if (xrow > TGT - 1) xrow = TGT - 1;
        xp[i] = X + ((size_t)(b * TGT + xrow)) * K + g * 8;
        wp[i] = W + ((size_t)(m0 + r)) * K + g * 8;
    }

    f32x4 acc[4][4] = {};

#define STAGE(XB, WB)                                                          \
    {                                                                          \
        _Pragma("unroll")                                                      \
        for (int i = 0; i < 4; ++i) {                                          \
            __builtin_amdgcn_global_load_lds((as1v)(void*)xp[i],               \
                (as3v)(void*)&XB[(wid * 4 + i) * 64], 16, 0, 0);               \
            __builtin_amdgcn_global_load_lds((as1v)(void*)wp[i],               \
                (as3v)(void*)&WB[(wid * 4 + i) * 64], 16, 0, 0);               \
            xp[i] += 64; wp[i] += 64;                                          \
        }                                                                      \
    }

    auto compute = [&](const i32x4* Xb, const i32x4* Wb) {
        const bf16x8* Xv = (const bf16x8*)Xb;
        const bf16x8* Wv = (const bf16x8*)Wb;
#pragma unroll
        for (int kk = 0; kk < 2; ++kk) {
            int sg = (kk * 4 + q) ^ (r15 & 7);
            bf16x8 af[4], bw[4];
#pragma unroll
            for (int ft = 0; ft < 4; ++ft)
                af[ft] = Xv[(wy * 64 + ft * 16 + r15) * 8 + sg];
#pragma unroll
            for (int fj = 0; fj < 4; ++fj)
                bw[fj] = Wv[(wx * 64 + fj * 16 + r15) * 8 + sg];
#pragma unroll
            for (int ft = 0; ft < 4; ++ft)
#pragma unroll
                for (int fj = 0; fj < 4; ++fj)
                    acc[ft][fj] = __builtin_amdgcn_mfma_f32_16x16x32_bf16(
                        af[ft], bw[fj], acc[ft][fj], 0, 0, 0);
        }
    };

    const int nkt = K >> 6;   // 10 / 16 / 8 — always even

    STAGE(Xs0, Ws0);

    for (int kt2 = 0; kt2 < nkt; kt2 += 2) {
        STAGE(Xs1, Ws1);
        asm volatile("s_waitcnt vmcnt(8)" ::: "memory");
        __builtin_amdgcn_s_barrier();
        __builtin_amdgcn_sched_barrier(0);
        compute(Xs0, Ws0);
        __builtin_amdgcn_sched_barrier(0);
        __builtin_amdgcn_s_barrier();

        if (kt2 + 2 < nkt) {
            STAGE(Xs0, Ws0);
            asm volatile("s_waitcnt vmcnt(8)" ::: "memory");
        } else {
            asm volatile("s_waitcnt vmcnt(0)" ::: "memory");
        }
        __builtin_amdgcn_s_barrier();
        __builtin_amdgcn_sched_barrier(0);
        compute(Xs1, Ws1);
        __builtin_amdgcn_sched_barrier(0);
        __builtin_amdgcn_s_barrier();
    }
#undef STAGE

    if (OUT_BF16) {
        // route through LDS -> coalesced 16B stores (reuses staging LDS;
        // last barrier above guarantees all LDS reads complete)
        __hip_bfloat16* Eb = (__hip_bfloat16*)smem;  // [128][136] padded
#pragma unroll
        for (int ft = 0; ft < 4; ++ft) {
#pragma unroll
            for (int r = 0; r < 4; ++r) {
                int tl = wy * 64 + ft * 16 + q * 4 + r;
#pragma unroll
                for (int fj = 0; fj < 4; ++fj) {
                    int ml = wx * 64 + fj * 16 + r15;
                    float v = acc[ft][fj][r];
                    if (bias) v += bias[m0 + ml];
                    if (RELU_OUT) v = fmaxf(v, 0.f);
                    Eb[tl * 136 + ml] = __float2bfloat16(v);
                }
            }
        }
        __syncthreads();
        int row = tid >> 1, half = tid & 1;
        int t = t0 + row;
        if (t < TGT) {
            __hip_bfloat16* dst = (__hip_bfloat16*)Y + ((size_t)(b * TGT + t)) * M + m0 + half * 64;
            const __hip_bfloat16* src = Eb + row * 136 + half * 64;
#pragma unroll
            for (int k = 0; k < 8; ++k)
                ((i32x4*)dst)[k] = ((const i32x4*)src)[k];
        }
    } else {
#pragma unroll
        for (int ft = 0; ft < 4; ++ft) {
#pragma unroll
            for (int r = 0; r < 4; ++r) {
                int t = t0 + wy * 64 + ft * 16 + q * 4 + r;
                if (t < TGT) {
                    size_t rowoff = ((size_t)(b * TGT + t)) * M;
#pragma unroll
                    for (int fj = 0; fj < 4; ++fj) {
                        int m = m0 + wx * 64 + fj * 16 + r15;
                        float v = acc[ft][fj][r];
                        if (bias) v += bias[m];
                        if (RELU_OUT) v = fmaxf(v, 0.f);
                        ((float*)Y)[rowoff + m] = v;
                    }
                }
            }
        }
    }
}

// ============================================================
extern "C" void kernel_launch(void* const* d_in, const int* in_sizes, int n_in,
                              void* d_out, int out_size, void* d_ws, size_t ws_size,
                              hipStream_t stream)
{
    const float* inputs   = (const float*)d_in[0];
    const float* cond     = (const float*)d_in[1];
    const float* input_w  = (const float*)d_in[2];
    const float* filter_w = (const float*)d_in[3];
    const float* gate_w   = (const float*)d_in[4];
    const float* res_w    = (const float*)d_in[5];
    const float* split_w  = (const float*)d_in[6];
    const float* gcf_w    = (const float*)d_in[7];
    const float* gcs_w    = (const float*)d_in[8];
    const float* f1_w     = (const float*)d_in[9];
    const float* f1_b     = (const float*)d_in[10];
    const float* f2_w     = (const float*)d_in[11];
    const float* f2_b     = (const float*)d_in[12];
    float* out = (float*)d_out;

    char* wsb = (char*)d_ws;
    const size_t RES_B   = (size_t)Bc * RCc * Lc * 4;
    const size_t OUTS_B  = (size_t)Bc * TGT * KTOT * 2;
    const size_t FIN_B   = (size_t)Bc * TGT * SCc * 2;
    const size_t H1_B    = (size_t)Bc * TGT * ECc * 2;
    const size_t W1_B    = (size_t)SCc * KTOT * 2;
    const size_t W2_B    = (size_t)ECc * SCc * 2;
    const size_t W3_B    = (size_t)OCc * ECc * 2;
    const size_t WFG_B   = (size_t)NL * 64 * 64 * 2;
    const size_t WR_B    = (size_t)NL * 32 * 64 * 2;

    float* res0              = (float*)wsb;                   size_t off = RES_B;
    float* res1              = (float*)(wsb + off);           off += RES_B;
    __hip_bfloat16* outsT    = (__hip_bfloat16*)(wsb + off);  off += OUTS_B;
    __hip_bfloat16* finalT   = (__hip_bfloat16*)(wsb + off);  off += FIN_B;
    __hip_bfloat16* h1T      = (__hip_bfloat16*)(wsb + off);  off += H1_B;
    __hip_bfloat16* Wp1      = (__hip_bfloat16*)(wsb + off);  off += W1_B;
    __hip_bfloat16* Wp2      = (__hip_bfloat16*)(wsb + off);  off += W2_B;
    __hip_bfloat16* Wp3      = (__hip_bfloat16*)(wsb + off);  off += W3_B;
    __hip_bfloat16* wfgp     = (__hip_bfloat16*)(wsb + off);  off += WFG_B;
    __hip_bfloat16* wrp      = (__hip_bfloat16*)(wsb + off);  off += WR_B;

    // prep: packs + input conv in one node
    {
        const int NTOT = SCc * KTOT + ECc * SCc + OCc * ECc + NL * 64 * 64;
        const int npack = (NTOT + 255) / 256;
        prep_kernel<<<npack + Bc * 128, 256, 0, stream>>>(
            inputs, input_w, res0,
            split_w, f1_w, f2_w, filter_w, gate_w, res_w,
            Wp1, Wp2, Wp3, wfgp, wrp, npack);
    }

    float* rin = res0;
    float* rout = res1;
    const dim3 lgrid(Lc / 64, Bc);

    for (int half = 0; half < 2; ++half) {
        int l0 = half * 10;
        layer_group<5, 1, 96><<<lgrid, 512, 0, stream>>>(
            rin, rout, outsT, wfgp, wrp, cond, gcf_w, gcs_w, l0);
        { float* t = rin; rin = rout; rout = t; }
        layer_group<3, 32, 288><<<lgrid, 512, 0, stream>>>(
            rin, rout, outsT, wfgp, wrp, cond, gcf_w, gcs_w, l0 + 5);
        { float* t = rin; rin = rout; rout = t; }
        {
            int li = l0 + 8;
            layer_mfma<false><<<lgrid, 256, 0, stream>>>(
                rin, rout, outsT, wfgp + (size_t)li * 4096, wrp + (size_t)li * 2048,
                cond, gcf_w + li * 5, gcs_w + li * 5, 256, li);
            float* t = rin; rin = rout; rout = t;
        }
        {
            int li = l0 + 9;
            if (li == NL - 1)
                layer_mfma<true><<<lgrid, 256, 0, stream>>>(
                    rin, rout, outsT, wfgp + (size_t)li * 4096, wrp + (size_t)li * 2048,
                    cond, gcf_w + li * 5, gcs_w + li * 5, 512, li);
            else
                layer_mfma<false><<<lgrid, 256, 0, stream>>>(
                    rin, rout, outsT, wfgp + (size_t)li * 4096, wrp + (size_t)li * 2048,
                    cond, gcf_w + li * 5, gcs_w + li * 5, 512, li);
            float* t = rin; rin = rout; rout = t;
        }
    }

    // G1: finalT = relu( outsT(12292x640) @ Wp1^T )   -> bf16 [t][1024]
    gemm_mfma<true, true><<<dim3(SCc / 128, Bc * TTILES), 256, 0, stream>>>(
        outsT, Wp1, nullptr, finalT, SCc, KTOT);

    // G2: h1T = relu( finalT @ Wp2^T + f1_b )         -> bf16 [t][512]
    gemm_mfma<true, true><<<dim3(ECc / 128, Bc * TTILES), 256, 0, stream>>>(
        finalT, Wp2, f1_b, h1T, ECc, SCc);

    // G3: out = h1T @ Wp3^T + f2_b                    -> fp32 [t][256] (final layout)
    gemm_mfma<false, false><<<dim3(OCc / 128, Bc * TTILES), 256, 0, stream>>>(
        h1T, Wp3, f2_b, out, OCc, ECc);
}